// Round 9
// baseline (6518.005 us; speedup 1.0000x reference)
//
#include <hip/hip_runtime.h>
#include <cfloat>
#include <cmath>

#define NB 128
#define NL 48
#define HID 512
#define NSLOT 48
#define NN 2560              // 5*HID output cols
#define NNODE (NB*NSLOT)     // 6144
#define AROWS (NB*(NL-1))    // 6016 phase-A pair rows

// ---------------- workspace layout (float units) ----------------
static const size_t offH    = 0;                                   // [B][48][512]
static const size_t offC    = offH  + (size_t)NNODE*HID;
static const size_t offCH   = offC  + (size_t)NNODE*HID;           // candidate h
static const size_t offCC   = offCH + (size_t)NNODE*HID;           // candidate c
static const size_t offLG   = offCC + (size_t)NNODE*HID;           // logits [B][48]
static const size_t offNXT  = offLG  + NNODE;                      // int
static const size_t offPRV  = offNXT + NNODE;                      // int
static const size_t offROWS = offPRV + NNODE;                      // int4 x 256
static const size_t offROWSA= offROWS + (size_t)4*(2*NB);          // int4 x 6016
static const size_t offROWSN= offROWSA + (size_t)4*AROWS;          // int x 6144 (compacted)
static const size_t offPROW = offROWSN + NNODE;                    // int x 128
static const size_t offNLIV = offPROW + 128;                       // int x 1 (+pad)
static const size_t offCNT8 = offNLIV + 32;                        // uint x 188 (47 iters x 4)
static const size_t offCNTB = offCNT8 + 192;                       // uint x 6016 (47 x 128)
static const size_t offV    = offCNTB + 6048;                      // 4*NB*NN floats (5.2MB)
static const size_t offBIG  = offV + (size_t)4*NB*NN;              // PL, PR (NNODE*NN each)
// total ~181.8 MB (ws >= 186.8 MB proven in round 4)

__device__ __forceinline__ float sigf(float x){ return 1.0f/(1.0f+expf(-x)); }

// ---------------- init: copy input -> H,C ; init links/logits ----------------
__global__ void k_init(const float* __restrict__ in, const int* __restrict__ len,
                       float* __restrict__ H, float* __restrict__ Cc,
                       float* __restrict__ LG, int* __restrict__ NXT,
                       int* __restrict__ PRV, int4* __restrict__ ROWS)
{
    int bs = blockIdx.x;            // b*48+s
    int b  = bs / NSLOT, s = bs % NSLOT;
    int t  = threadIdx.x;           // 256 threads, 1 float4 each
    const float4* inrow = (const float4*)(in + (size_t)bs*2*HID);
    float4 v = inrow[t];
    if (t < 128) ((float4*)(H  + (size_t)bs*HID))[t]       = v;
    else         ((float4*)(Cc + (size_t)bs*HID))[t - 128] = v;
    if (t == 0) {
        int lb = len[b];
        NXT[bs] = (s+1 < lb) ? s+1 : -1;
        PRV[bs] = (s > 0 && s < lb) ? s-1 : -1;
        LG[bs]  = -FLT_MAX;
        if (s == 0) {
            ROWS[b*2+0] = make_int4(0,0,0,-1);
            ROWS[b*2+1] = make_int4(0,0,0,-1);
        }
    }
}

// ---------------- descriptors + counter zeroing ----------------
__global__ void k_descA(const int* __restrict__ len, int4* __restrict__ ROWSA,
                        int* __restrict__ ROWSN, int* __restrict__ NLIVE,
                        unsigned int* __restrict__ CNT8, unsigned int* __restrict__ CNTB)
{
    __shared__ int off[NB+1];
    int t = threadIdx.x;            // single block, 256 threads
    if (t == 0){
        int acc = 0;
        for (int b=0;b<NB;++b){ off[b]=acc; acc += len[b]; }
        off[NB] = acc;
        NLIVE[0] = (acc + 127) & ~127;
    }
    __syncthreads();
    int nlive = off[NB];
    int npad  = (nlive + 127) & ~127;
    for (int r = t; r < AROWS; r += 256){
        int b = r/(NL-1), s = r%(NL-1);
        int lb = len[b];
        ROWSA[r] = make_int4(b, s, s+1, (s <= lb-2) ? s : -1);
    }
    for (int x = t; x < NNODE; x += 256){
        int b = x / NSLOT, s = x % NSLOT;
        if (s < len[b]) ROWSN[off[b] + s] = x;
    }
    for (int x = nlive + t; x < npad; x += 256) ROWSN[x] = 0;
    for (int x = t; x < 188;  x += 256) CNT8[x] = 0u;
    for (int x = t; x < 6016; x += 256) CNTB[x] = 0u;
}

// ================= phase-A split-W product GEMM (proven 8x4 micro) =================
template<int MI, int KT>
__global__ __launch_bounds__(256, 4)
void k_gemmP(const int* __restrict__ rows, const int* __restrict__ NLIVE,
             const float* __restrict__ H, const float* __restrict__ W,
             float* __restrict__ PL, float* __restrict__ PR)
{
    constexpr int BM  = 16*MI;
    constexpr int AF4 = BM/64;
    constexpr int LDA = BM + 4;
    constexpr int LDB = 68;

    const int m0  = blockIdx.x*BM;
    if (m0 >= NLIVE[0]) return;     // compacted: skip dead tiles

    __shared__ float As[2][16*LDA];
    __shared__ float Bs[2][16*LDB];

    const int t   = threadIdx.x;
    const int vn0 = blockIdx.y*64;
    const int side = (vn0 >= NN);
    const int n0  = side ? vn0 - NN : vn0;
    float* OUT = side ? PR : PL;

    int aoff[AF4], arow[AF4], aseg[AF4];
    #pragma unroll
    for (int j=0;j<AF4;++j){
        int f = t*AF4 + j;
        arow[j] = f >> 2; aseg[j] = f & 3;
        aoff[j] = rows[m0 + arow[j]]*HID + aseg[j]*4;
    }
    const int brow = t >> 2, bseg = t & 3;
    const float* wptr = W + (size_t)(n0 + brow)*1024 + side*HID + bseg*4;

    const int tm = t >> 4, tn = t & 15;

    float acc[MI][4];
    #pragma unroll
    for (int mi=0;mi<MI;++mi)
        #pragma unroll
        for (int j=0;j<4;++j) acc[mi][j]=0.f;

    float4 av[AF4], bv;
    auto gload = [&](int kt){
        int kg = kt*16;
        #pragma unroll
        for (int j=0;j<AF4;++j) av[j] = *(const float4*)(H + aoff[j] + kg);
        bv = *(const float4*)(wptr + kg);
    };
    auto swrite = [&](int buf){
        #pragma unroll
        for (int j=0;j<AF4;++j){
            As[buf][(aseg[j]*4+0)*LDA + arow[j]] = av[j].x;
            As[buf][(aseg[j]*4+1)*LDA + arow[j]] = av[j].y;
            As[buf][(aseg[j]*4+2)*LDA + arow[j]] = av[j].z;
            As[buf][(aseg[j]*4+3)*LDA + arow[j]] = av[j].w;
        }
        Bs[buf][(bseg*4+0)*LDB + brow] = bv.x;
        Bs[buf][(bseg*4+1)*LDB + brow] = bv.y;
        Bs[buf][(bseg*4+2)*LDB + brow] = bv.z;
        Bs[buf][(bseg*4+3)*LDB + brow] = bv.w;
    };

    gload(0); swrite(0); __syncthreads();

    for (int kt=0; kt<KT; ++kt){
        int buf = kt & 1;
        if (kt+1 < KT) gload(kt+1);
        #pragma unroll
        for (int k=0;k<16;++k){
            float a[MI];
            #pragma unroll
            for (int mi=0;mi<MI;mi+=4){
                float4 a4 = *(const float4*)&As[buf][k*LDA + tm*MI + mi];
                a[mi]=a4.x; a[mi+1]=a4.y; a[mi+2]=a4.z; a[mi+3]=a4.w;
            }
            float4 b4 = *(const float4*)&Bs[buf][k*LDB + tn*4];
            #pragma unroll
            for (int mi=0;mi<MI;++mi){
                acc[mi][0] = fmaf(a[mi], b4.x, acc[mi][0]);
                acc[mi][1] = fmaf(a[mi], b4.y, acc[mi][1]);
                acc[mi][2] = fmaf(a[mi], b4.z, acc[mi][2]);
                acc[mi][3] = fmaf(a[mi], b4.w, acc[mi][3]);
            }
        }
        if (kt+1 < KT) swrite(buf^1);
        __syncthreads();
    }

    #pragma unroll
    for (int mi=0;mi<MI;++mi){
        int row = m0 + tm*MI + mi;
        float4 o; o.x=acc[mi][0]; o.y=acc[mi][1]; o.z=acc[mi][2]; o.w=acc[mi][3];
        *(float4*)(OUT + (size_t)rows[row]*NN + n0 + tn*4) = o;
    }
}

// ---------------- phase-A combine ----------------
__global__ void k_combineP(const int4* __restrict__ rows,
                           const float* __restrict__ PL, const float* __restrict__ PR,
                           const float* __restrict__ Cc, const float* __restrict__ bias,
                           const float* __restrict__ q,
                           float* __restrict__ CH, float* __restrict__ CC,
                           float* __restrict__ LG)
{
    int4 rd = rows[blockIdx.x];
    if (rd.w < 0) return;
    int t = threadIdx.x;
    int b = rd.x, sl = rd.y, sr = rd.z, dst = rd.w;
    const float* pl = PL + (size_t)(b*NSLOT+sl)*NN;
    const float* pr = PR + (size_t)(b*NSLOT+sr)*NN;
    const float* cl = Cc + (size_t)(b*NSLOT+sl)*HID;
    const float* cr = Cc + (size_t)(b*NSLOT+sr)*HID;
    float part = 0.f;
    #pragma unroll
    for (int h2=0; h2<2; ++h2){
        int c = t + h2*256;
        float v[5];
        #pragma unroll
        for (int g=0; g<5; ++g)
            v[g] = pl[g*HID+c] + pr[g*HID+c] + bias[g*HID+c];
        float cn = cl[c]*sigf(v[1]+1.f) + cr[c]*sigf(v[2]+1.f) + tanhf(v[3])*sigf(v[0]);
        float hn = sigf(v[4])*tanhf(cn);
        CH[(size_t)(b*NSLOT+dst)*HID + c] = hn;
        CC[(size_t)(b*NSLOT+dst)*HID + c] = cn;
        part += q[c]*hn;
    }
    __shared__ float red[4];
    #pragma unroll
    for (int off=32; off; off>>=1) part += __shfl_xor(part, off);
    if ((t & 63) == 0) red[t>>6] = part;
    __syncthreads();
    if (t == 0) LG[b*NSLOT + dst] = red[0]+red[1]+red[2]+red[3];
}

// ---------------- step 0: argmax, commit, relink ----------------
__global__ void k_step0(const int* __restrict__ len,
                        float* __restrict__ H, float* __restrict__ Cc,
                        const float* __restrict__ CH, const float* __restrict__ CC,
                        float* __restrict__ LG, int* __restrict__ NXT,
                        int* __restrict__ PRV, int4* __restrict__ ROWS,
                        int* __restrict__ PROW)
{
    int b = blockIdx.x, lane = threadIdx.x;   // block = 64 = 1 wave
    int base = b*NSLOT;

    float val = (lane < NSLOT) ? LG[base+lane] : -FLT_MAX;
    int idx = lane;
    for (int off=1; off<64; off<<=1){
        float oval = __shfl_xor(val, off);
        int   oidx = __shfl_xor(idx, off);
        if (oval > val || (oval == val && oidx < idx)){ val = oval; idx = oidx; }
    }
    int sstar = idx;
    int r  = NXT[base+sstar];
    int qn = NXT[base+r];
    int p  = PRV[base+sstar];

    const float4* sh = (const float4*)(CH + (size_t)(base+sstar)*HID);
    const float4* sc = (const float4*)(CC + (size_t)(base+sstar)*HID);
    float4* dh = (float4*)(H  + (size_t)(base+sstar)*HID);
    float4* dc = (float4*)(Cc + (size_t)(base+sstar)*HID);
    dh[lane] = sh[lane]; dh[lane+64] = sh[lane+64];
    dc[lane] = sc[lane]; dc[lane+64] = sc[lane+64];

    if (lane==0){
        NXT[base+sstar] = qn;
        if (qn >= 0) PRV[base+qn] = sstar;
        LG[base+r] = -FLT_MAX;
        if (qn < 0) LG[base+sstar] = -FLT_MAX;
        ROWS[b*2+0] = (p  >= 0) ? make_int4(b, p, sstar, p)      : make_int4(0,0,0,-1);
        ROWS[b*2+1] = (qn >= 0) ? make_int4(b, sstar, qn, sstar) : make_int4(0,0,0,-1);
        PROW[b] = base + sstar;
    }
}

// ================= fused step: GEMM + combine + argmax/commit in ONE kernel =================
// grid = 320 linear blocks x 256 threads, all co-resident (launch_bounds 256,3 -> >=768 slots).
// Stage G  (all 320): KS=2 GEMM tile -> V; ticket CNT8[i*4 + mx*2 + side] (target 80).
// Stage C1 (bid<256): b=bid>>1, e=bid&1; spin on the 80 producer blocks; V-sum -> cache ->
//                     gates -> CH/CC + logit -> LG; ticket CNTB[i*128+b] (target 2).
// Stage C2 (bid<128): b=bid; spin per-batch; argmax + commit + relink.
__global__ __launch_bounds__(256, 3)
void k_stepFused(int i, const int* __restrict__ len,
                 const float* __restrict__ H_, const float* __restrict__ W,
                 float* __restrict__ V,
                 float* __restrict__ PL, float* __restrict__ PR,
                 int4* __restrict__ ROWS, int* __restrict__ PROW,
                 float* __restrict__ H, float* __restrict__ Cc,
                 float* __restrict__ CH, float* __restrict__ CC,
                 float* __restrict__ LG, int* __restrict__ NXT,
                 int* __restrict__ PRV,
                 const float* __restrict__ bias, const float* __restrict__ q,
                 unsigned int* __restrict__ CNT8, unsigned int* __restrict__ CNTB)
{
    constexpr int MI = 4, KT = 16;
    constexpr int LDA = 68, LDB = 68;
    __shared__ float As[2][16*LDA];
    __shared__ float Bs[2][16*LDB];
    __shared__ float red[4];
    __shared__ int ss[1];

    const int bid = blockIdx.x;
    const int t = threadIdx.x;

    // ===== Stage G: GEMM tile =====
    {
        const int mx = bid & 1;
        const int kz = (bid >> 1) & 1;
        const int ny = bid >> 2;              // 0..79
        const int side = (ny >= 40);
        const int n0 = (ny - 40*side)*64;
        const int m0 = mx*64;
        const int kg0 = kz*KT*16;

        const int arow = t >> 2, aseg = t & 3;
        const float* aptr = H_ + (size_t)PROW[m0 + arow]*HID + aseg*4 + kg0;
        const float* bptr = W + (size_t)(n0 + arow)*1024 + side*HID + aseg*4 + kg0;

        const int tm = t >> 4, tn = t & 15;

        float acc[MI][4];
        #pragma unroll
        for (int mi=0;mi<MI;++mi)
            #pragma unroll
            for (int j=0;j<4;++j) acc[mi][j]=0.f;

        float4 av, bv;
        auto gload = [&](int kt){
            av = *(const float4*)(aptr + kt*16);
            bv = *(const float4*)(bptr + kt*16);
        };
        auto swrite = [&](int buf){
            As[buf][(aseg*4+0)*LDA + arow] = av.x;
            As[buf][(aseg*4+1)*LDA + arow] = av.y;
            As[buf][(aseg*4+2)*LDA + arow] = av.z;
            As[buf][(aseg*4+3)*LDA + arow] = av.w;
            Bs[buf][(aseg*4+0)*LDB + arow] = bv.x;
            Bs[buf][(aseg*4+1)*LDB + arow] = bv.y;
            Bs[buf][(aseg*4+2)*LDB + arow] = bv.z;
            Bs[buf][(aseg*4+3)*LDB + arow] = bv.w;
        };

        gload(0); swrite(0); __syncthreads();

        for (int kt=0; kt<KT; ++kt){
            int buf = kt & 1;
            if (kt+1 < KT) gload(kt+1);
            #pragma unroll
            for (int k=0;k<16;++k){
                float4 a4 = *(const float4*)&As[buf][k*LDA + tm*MI];
                float4 b4 = *(const float4*)&Bs[buf][k*LDB + tn*4];
                float a[4] = {a4.x,a4.y,a4.z,a4.w};
                #pragma unroll
                for (int mi=0;mi<MI;++mi){
                    acc[mi][0] = fmaf(a[mi], b4.x, acc[mi][0]);
                    acc[mi][1] = fmaf(a[mi], b4.y, acc[mi][1]);
                    acc[mi][2] = fmaf(a[mi], b4.z, acc[mi][2]);
                    acc[mi][3] = fmaf(a[mi], b4.w, acc[mi][3]);
                }
            }
            if (kt+1 < KT) swrite(buf^1);
            __syncthreads();
        }

        #pragma unroll
        for (int mi=0;mi<MI;++mi){
            int row = m0 + tm*MI + mi;       // = batch index
            float4 o; o.x=acc[mi][0]; o.y=acc[mi][1]; o.z=acc[mi][2]; o.w=acc[mi][3];
            *(float4*)(V + ((size_t)(kz*2+side)*NB + row)*NN + n0 + tn*4) = o;
        }

        __threadfence();
        __syncthreads();
        if (t == 0)
            __hip_atomic_fetch_add(&CNT8[i*4 + mx*2 + side], 1u,
                                   __ATOMIC_RELEASE, __HIP_MEMORY_SCOPE_AGENT);
    }

    if (bid >= 256) return;

    // ===== Stage C1: per-(batch,pair) combine =====
    {
        const int b = bid >> 1, e = bid & 1;
        const int base = b*NSLOT;
        const int sideR = e ^ 1;             // e=0 reads PR-side partials, e=1 PL-side
        if (t == 0){
            while (__hip_atomic_load(&CNT8[i*4 + (b>>6)*2 + sideR],
                                     __ATOMIC_ACQUIRE, __HIP_MEMORY_SCOPE_AGENT) < 80u) {}
        }
        __syncthreads();

        int4 rd = ROWS[b*2+e];
        bool valid = (rd.w >= 0);
        int node = PROW[b];
        float* CACHE = (e == 0) ? PR : PL;

        float vnew[10];
        #pragma unroll
        for (int jj=0;jj<10;++jj){
            int c = jj*256 + t;
            vnew[jj] = V[((size_t)(0+sideR)*NB + b)*NN + c]
                     + V[((size_t)(2+sideR)*NB + b)*NN + c];
            CACHE[(size_t)node*NN + c] = vnew[jj];
        }

        float part = 0.f;
        if (valid){
            const float* OTH = e ? (PR + (size_t)(base+rd.z)*NN)
                                 : (PL + (size_t)(base+rd.y)*NN);
            const float* cl = Cc + (size_t)(base+rd.y)*HID;
            const float* cr = Cc + (size_t)(base+rd.z)*HID;
            int dst = rd.w;
            #pragma unroll
            for (int h2=0; h2<2; ++h2){
                int c = t + h2*256;
                float v[5];
                #pragma unroll
                for (int g=0; g<5; ++g)
                    v[g] = OTH[g*HID + c] + vnew[g*2+h2] + bias[g*HID + c];
                float cn = cl[c]*sigf(v[1]+1.f) + cr[c]*sigf(v[2]+1.f) + tanhf(v[3])*sigf(v[0]);
                float hn = sigf(v[4])*tanhf(cn);
                CH[(size_t)(base+dst)*HID + c] = hn;
                CC[(size_t)(base+dst)*HID + c] = cn;
                part += q[c]*hn;
            }
        }
        #pragma unroll
        for (int off=32; off; off>>=1) part += __shfl_xor(part, off);
        if ((t & 63) == 0) red[t>>6] = part;
        __syncthreads();
        if (t == 0 && valid)
            LG[base + rd.w] = red[0]+red[1]+red[2]+red[3];

        __threadfence();
        __syncthreads();
        if (t == 0)
            __hip_atomic_fetch_add(&CNTB[i*128 + b], 1u,
                                   __ATOMIC_RELEASE, __HIP_MEMORY_SCOPE_AGENT);
    }

    if (bid >= 128) return;

    // ===== Stage C2: per-batch argmax + commit + relink =====
    {
        const int b = bid;
        const int base = b*NSLOT;
        if (t == 0){
            while (__hip_atomic_load(&CNTB[i*128 + b],
                                     __ATOMIC_ACQUIRE, __HIP_MEMORY_SCOPE_AGENT) < 2u) {}
        }
        __syncthreads();

        int lb = len[b];
        if (i > lb-2){
            if (t==0){
                ROWS[b*2+0]=make_int4(0,0,0,-1);
                ROWS[b*2+1]=make_int4(0,0,0,-1);
                PROW[b]=base;
            }
            return;
        }

        if (t < 64){
            float val = (t < NSLOT)? LG[base+t] : -FLT_MAX;
            int idx = t;
            for (int off=1; off<64; off<<=1){
                float ov=__shfl_xor(val,off); int oi=__shfl_xor(idx,off);
                if (ov>val || (ov==val && oi<idx)){ val=ov; idx=oi; }
            }
            if (t==0) ss[0]=idx;
        }
        __syncthreads();
        int sstar = ss[0];
        {
            const float4* sh = (const float4*)(CH + (size_t)(base+sstar)*HID);
            const float4* sc = (const float4*)(CC + (size_t)(base+sstar)*HID);
            float4* dh = (float4*)(H  + (size_t)(base+sstar)*HID);
            float4* dc = (float4*)(Cc + (size_t)(base+sstar)*HID);
            if (t < 128) dh[t] = sh[t];
            else         dc[t-128] = sc[t-128];
        }
        if (t == 0){
            int r  = NXT[base+sstar];
            int qn = NXT[base+r];
            int p  = PRV[base+sstar];
            NXT[base+sstar] = qn;
            if (qn >= 0) PRV[base+qn] = sstar;
            LG[base+r] = -FLT_MAX;
            if (qn < 0) LG[base+sstar] = -FLT_MAX;
            ROWS[b*2+0] = (p  >= 0) ? make_int4(b, p, sstar, p)      : make_int4(0,0,0,-1);
            ROWS[b*2+1] = (qn >= 0) ? make_int4(b, sstar, qn, sstar) : make_int4(0,0,0,-1);
            PROW[b] = base + sstar;
        }
    }
}

// ---------------- output: root = slot 0 ----------------
__global__ void k_out(const float* __restrict__ H, float* __restrict__ out)
{
    int b = blockIdx.x, t = threadIdx.x;       // 128 threads x float4
    ((float4*)out)[b*128 + t] = ((const float4*)(H + (size_t)b*NSLOT*HID))[t];
}

extern "C" void kernel_launch(void* const* d_in, const int* in_sizes, int n_in,
                              void* d_out, int out_size, void* d_ws, size_t ws_size,
                              hipStream_t stream)
{
    const float* in   = (const float*)d_in[0];
    const float* W    = (const float*)d_in[1];
    const float* bias = (const float*)d_in[2];
    const float* q    = (const float*)d_in[3];
    const int*   len  = (const int*)d_in[4];

    float* ws = (float*)d_ws;
    float* H  = ws + offH;
    float* Cc = ws + offC;
    float* CH = ws + offCH;
    float* CC = ws + offCC;
    float* LG = ws + offLG;
    int* NXT  = (int*)(ws + offNXT);
    int* PRV  = (int*)(ws + offPRV);
    int4* ROWS  = (int4*)(ws + offROWS);
    int4* ROWSA = (int4*)(ws + offROWSA);
    int*  ROWSN = (int*)(ws + offROWSN);
    int*  PROW  = (int*)(ws + offPROW);
    int*  NLIVE = (int*)(ws + offNLIV);
    unsigned int* CNT8 = (unsigned int*)(ws + offCNT8);
    unsigned int* CNTB = (unsigned int*)(ws + offCNTB);
    float* V  = ws + offV;
    float* PL = ws + offBIG;
    float* PR = PL + (size_t)NNODE*NN;
    float* out = (float*)d_out;

    k_init <<<dim3(NNODE), dim3(256), 0, stream>>>(in, len, H, Cc, LG, NXT, PRV, ROWS);
    k_descA<<<dim3(1), dim3(256), 0, stream>>>(len, ROWSA, ROWSN, NLIVE, CNT8, CNTB);

    // phase A: per-node products (compacted rows) + pair combine + first merge
    k_gemmP<8,32><<<dim3(NNODE/128, 2*NN/64), dim3(256), 0, stream>>>(ROWSN, NLIVE, H, W, PL, PR);
    k_combineP<<<dim3(AROWS), dim3(256), 0, stream>>>(ROWSA, PL, PR, Cc, bias, q, CH, CC, LG);
    k_step0<<<dim3(NB), dim3(64), 0, stream>>>(len, H, Cc, CH, CC, LG, NXT, PRV, ROWS, PROW);

    // step loop: ONE fused kernel per iteration
    for (int i = 1; i < NL-1; ++i){
        k_stepFused<<<dim3(320), dim3(256), 0, stream>>>(
            i, len, H, W, V, PL, PR, ROWS, PROW, H, Cc, CH, CC, LG, NXT, PRV,
            bias, q, CNT8, CNTB);
    }
    k_out<<<dim3(NB), dim3(128), 0, stream>>>(H, out);
}

// Round 10
// 6307.513 us; speedup vs baseline: 1.0334x; 1.0334x over previous
//
#include <hip/hip_runtime.h>
#include <cfloat>
#include <cmath>

#define NB 128
#define NL 48
#define HID 512
#define NSLOT 48
#define NN 2560              // 5*HID output cols
#define NNODE (NB*NSLOT)     // 6144
#define AROWS (NB*(NL-1))    // 6016 phase-A pair rows

// ---------------- workspace layout (float units) ----------------
static const size_t offH    = 0;                                   // [B][48][512]
static const size_t offC    = offH  + (size_t)NNODE*HID;
static const size_t offCH   = offC  + (size_t)NNODE*HID;           // candidate h
static const size_t offCC   = offCH + (size_t)NNODE*HID;           // candidate c
static const size_t offLG   = offCC + (size_t)NNODE*HID;           // logits [B][48]
static const size_t offNXT  = offLG  + NNODE;                      // int
static const size_t offPRV  = offNXT + NNODE;                      // int
static const size_t offROWS = offPRV + NNODE;                      // int4 x 256
static const size_t offROWSA= offROWS + (size_t)4*(2*NB);          // int4 x 6016
static const size_t offROWSN= offROWSA + (size_t)4*AROWS;          // int x 6144 (compacted)
static const size_t offPROW = offROWSN + NNODE;                    // int x 128
static const size_t offNLIV = offPROW + 128;                       // int x 1 (+pad)
static const size_t offFG   = offNLIV + 32;                        // uint x 320 (+pad 384)
static const size_t offFC   = offFG + 384;                         // uint x 256
static const size_t offV    = offFC + 256;                         // 4*NB*NN floats (5.2MB)
static const size_t offBIG  = offV + (size_t)4*NB*NN;              // PL, PR (NNODE*NN each)
// total ~181.8 MB (ws >= 186.8 MB proven in round 4)

__device__ __forceinline__ float sigf(float x){ return 1.0f/(1.0f+expf(-x)); }

// ---------------- init: copy input -> H,C ; init links/logits ----------------
__global__ void k_init(const float* __restrict__ in, const int* __restrict__ len,
                       float* __restrict__ H, float* __restrict__ Cc,
                       float* __restrict__ LG, int* __restrict__ NXT,
                       int* __restrict__ PRV, int4* __restrict__ ROWS)
{
    int bs = blockIdx.x;            // b*48+s
    int b  = bs / NSLOT, s = bs % NSLOT;
    int t  = threadIdx.x;           // 256 threads, 1 float4 each
    const float4* inrow = (const float4*)(in + (size_t)bs*2*HID);
    float4 v = inrow[t];
    if (t < 128) ((float4*)(H  + (size_t)bs*HID))[t]       = v;
    else         ((float4*)(Cc + (size_t)bs*HID))[t - 128] = v;
    if (t == 0) {
        int lb = len[b];
        NXT[bs] = (s+1 < lb) ? s+1 : -1;
        PRV[bs] = (s > 0 && s < lb) ? s-1 : -1;
        LG[bs]  = -FLT_MAX;
        if (s == 0) {
            ROWS[b*2+0] = make_int4(0,0,0,-1);
            ROWS[b*2+1] = make_int4(0,0,0,-1);
        }
    }
}

// ---------------- descriptors + flag zeroing ----------------
__global__ void k_descA(const int* __restrict__ len, int4* __restrict__ ROWSA,
                        int* __restrict__ ROWSN, int* __restrict__ NLIVE,
                        unsigned int* __restrict__ FG, unsigned int* __restrict__ FC)
{
    __shared__ int off[NB+1];
    int t = threadIdx.x;            // single block, 256 threads
    if (t == 0){
        int acc = 0;
        for (int b=0;b<NB;++b){ off[b]=acc; acc += len[b]; }
        off[NB] = acc;
        NLIVE[0] = (acc + 127) & ~127;
    }
    __syncthreads();
    int nlive = off[NB];
    int npad  = (nlive + 127) & ~127;
    for (int r = t; r < AROWS; r += 256){
        int b = r/(NL-1), s = r%(NL-1);
        int lb = len[b];
        ROWSA[r] = make_int4(b, s, s+1, (s <= lb-2) ? s : -1);
    }
    for (int x = t; x < NNODE; x += 256){
        int b = x / NSLOT, s = x % NSLOT;
        if (s < len[b]) ROWSN[off[b] + s] = x;
    }
    for (int x = nlive + t; x < npad; x += 256) ROWSN[x] = 0;
    for (int x = t; x < 384; x += 256) FG[x] = 0u;
    for (int x = t; x < 256; x += 256) FC[x] = 0u;
}

// ================= phase-A split-W product GEMM (proven 8x4 micro) =================
template<int MI, int KT>
__global__ __launch_bounds__(256, 4)
void k_gemmP(const int* __restrict__ rows, const int* __restrict__ NLIVE,
             const float* __restrict__ H, const float* __restrict__ W,
             float* __restrict__ PL, float* __restrict__ PR)
{
    constexpr int BM  = 16*MI;
    constexpr int AF4 = BM/64;
    constexpr int LDA = BM + 4;
    constexpr int LDB = 68;

    const int m0  = blockIdx.x*BM;
    if (m0 >= NLIVE[0]) return;     // compacted: skip dead tiles

    __shared__ float As[2][16*LDA];
    __shared__ float Bs[2][16*LDB];

    const int t   = threadIdx.x;
    const int vn0 = blockIdx.y*64;
    const int side = (vn0 >= NN);
    const int n0  = side ? vn0 - NN : vn0;
    float* OUT = side ? PR : PL;

    int aoff[AF4], arow[AF4], aseg[AF4];
    #pragma unroll
    for (int j=0;j<AF4;++j){
        int f = t*AF4 + j;
        arow[j] = f >> 2; aseg[j] = f & 3;
        aoff[j] = rows[m0 + arow[j]]*HID + aseg[j]*4;
    }
    const int brow = t >> 2, bseg = t & 3;
    const float* wptr = W + (size_t)(n0 + brow)*1024 + side*HID + bseg*4;

    const int tm = t >> 4, tn = t & 15;

    float acc[MI][4];
    #pragma unroll
    for (int mi=0;mi<MI;++mi)
        #pragma unroll
        for (int j=0;j<4;++j) acc[mi][j]=0.f;

    float4 av[AF4], bv;
    auto gload = [&](int kt){
        int kg = kt*16;
        #pragma unroll
        for (int j=0;j<AF4;++j) av[j] = *(const float4*)(H + aoff[j] + kg);
        bv = *(const float4*)(wptr + kg);
    };
    auto swrite = [&](int buf){
        #pragma unroll
        for (int j=0;j<AF4;++j){
            As[buf][(aseg[j]*4+0)*LDA + arow[j]] = av[j].x;
            As[buf][(aseg[j]*4+1)*LDA + arow[j]] = av[j].y;
            As[buf][(aseg[j]*4+2)*LDA + arow[j]] = av[j].z;
            As[buf][(aseg[j]*4+3)*LDA + arow[j]] = av[j].w;
        }
        Bs[buf][(bseg*4+0)*LDB + brow] = bv.x;
        Bs[buf][(bseg*4+1)*LDB + brow] = bv.y;
        Bs[buf][(bseg*4+2)*LDB + brow] = bv.z;
        Bs[buf][(bseg*4+3)*LDB + brow] = bv.w;
    };

    gload(0); swrite(0); __syncthreads();

    for (int kt=0; kt<KT; ++kt){
        int buf = kt & 1;
        if (kt+1 < KT) gload(kt+1);
        #pragma unroll
        for (int k=0;k<16;++k){
            float a[MI];
            #pragma unroll
            for (int mi=0;mi<MI;mi+=4){
                float4 a4 = *(const float4*)&As[buf][k*LDA + tm*MI + mi];
                a[mi]=a4.x; a[mi+1]=a4.y; a[mi+2]=a4.z; a[mi+3]=a4.w;
            }
            float4 b4 = *(const float4*)&Bs[buf][k*LDB + tn*4];
            #pragma unroll
            for (int mi=0;mi<MI;++mi){
                acc[mi][0] = fmaf(a[mi], b4.x, acc[mi][0]);
                acc[mi][1] = fmaf(a[mi], b4.y, acc[mi][1]);
                acc[mi][2] = fmaf(a[mi], b4.z, acc[mi][2]);
                acc[mi][3] = fmaf(a[mi], b4.w, acc[mi][3]);
            }
        }
        if (kt+1 < KT) swrite(buf^1);
        __syncthreads();
    }

    #pragma unroll
    for (int mi=0;mi<MI;++mi){
        int row = m0 + tm*MI + mi;
        float4 o; o.x=acc[mi][0]; o.y=acc[mi][1]; o.z=acc[mi][2]; o.w=acc[mi][3];
        *(float4*)(OUT + (size_t)rows[row]*NN + n0 + tn*4) = o;
    }
}

// ---------------- phase-A combine ----------------
__global__ void k_combineP(const int4* __restrict__ rows,
                           const float* __restrict__ PL, const float* __restrict__ PR,
                           const float* __restrict__ Cc, const float* __restrict__ bias,
                           const float* __restrict__ q,
                           float* __restrict__ CH, float* __restrict__ CC,
                           float* __restrict__ LG)
{
    int4 rd = rows[blockIdx.x];
    if (rd.w < 0) return;
    int t = threadIdx.x;
    int b = rd.x, sl = rd.y, sr = rd.z, dst = rd.w;
    const float* pl = PL + (size_t)(b*NSLOT+sl)*NN;
    const float* pr = PR + (size_t)(b*NSLOT+sr)*NN;
    const float* cl = Cc + (size_t)(b*NSLOT+sl)*HID;
    const float* cr = Cc + (size_t)(b*NSLOT+sr)*HID;
    float part = 0.f;
    #pragma unroll
    for (int h2=0; h2<2; ++h2){
        int c = t + h2*256;
        float v[5];
        #pragma unroll
        for (int g=0; g<5; ++g)
            v[g] = pl[g*HID+c] + pr[g*HID+c] + bias[g*HID+c];
        float cn = cl[c]*sigf(v[1]+1.f) + cr[c]*sigf(v[2]+1.f) + tanhf(v[3])*sigf(v[0]);
        float hn = sigf(v[4])*tanhf(cn);
        CH[(size_t)(b*NSLOT+dst)*HID + c] = hn;
        CC[(size_t)(b*NSLOT+dst)*HID + c] = cn;
        part += q[c]*hn;
    }
    __shared__ float red[4];
    #pragma unroll
    for (int off=32; off; off>>=1) part += __shfl_xor(part, off);
    if ((t & 63) == 0) red[t>>6] = part;
    __syncthreads();
    if (t == 0) LG[b*NSLOT + dst] = red[0]+red[1]+red[2]+red[3];
}

// ---------------- step 0: argmax, commit, relink ----------------
__global__ void k_step0(const int* __restrict__ len,
                        float* __restrict__ H, float* __restrict__ Cc,
                        const float* __restrict__ CH, const float* __restrict__ CC,
                        float* __restrict__ LG, int* __restrict__ NXT,
                        int* __restrict__ PRV, int4* __restrict__ ROWS,
                        int* __restrict__ PROW)
{
    int b = blockIdx.x, lane = threadIdx.x;   // block = 64 = 1 wave
    int base = b*NSLOT;

    float val = (lane < NSLOT) ? LG[base+lane] : -FLT_MAX;
    int idx = lane;
    for (int off=1; off<64; off<<=1){
        float oval = __shfl_xor(val, off);
        int   oidx = __shfl_xor(idx, off);
        if (oval > val || (oval == val && oidx < idx)){ val = oval; idx = oidx; }
    }
    int sstar = idx;
    int r  = NXT[base+sstar];
    int qn = NXT[base+r];
    int p  = PRV[base+sstar];

    const float4* sh = (const float4*)(CH + (size_t)(base+sstar)*HID);
    const float4* sc = (const float4*)(CC + (size_t)(base+sstar)*HID);
    float4* dh = (float4*)(H  + (size_t)(base+sstar)*HID);
    float4* dc = (float4*)(Cc + (size_t)(base+sstar)*HID);
    dh[lane] = sh[lane]; dh[lane+64] = sh[lane+64];
    dc[lane] = sc[lane]; dc[lane+64] = sc[lane+64];

    if (lane==0){
        NXT[base+sstar] = qn;
        if (qn >= 0) PRV[base+qn] = sstar;
        LG[base+r] = -FLT_MAX;
        if (qn < 0) LG[base+sstar] = -FLT_MAX;
        ROWS[b*2+0] = (p  >= 0) ? make_int4(b, p, sstar, p)      : make_int4(0,0,0,-1);
        ROWS[b*2+1] = (qn >= 0) ? make_int4(b, sstar, qn, sstar) : make_int4(0,0,0,-1);
        PROW[b] = base + sstar;
    }
}

// ================= fused step: GEMM + combine + argmax/commit, flag barriers =================
// grid = 320 blocks x 256 threads, all co-resident ((256,3) -> 768 slots >= 320).
// Stage G  (all 320): KS=2 GEMM tile -> V; release: FG[bid] = i (320 distinct words).
// Stage C1 (bid<256): (b,e); wave0 polls its 80 producer flags in parallel; V-sum -> cache
//                     -> gates -> CH/CC + logit; release FC[b*2+e] = i.
// Stage C2 (bid<128): b; polls FC[b*2..b*2+1]; argmax + commit + relink.
__global__ __launch_bounds__(256, 3)
void k_stepOne(int i, const int* __restrict__ len,
               const float* __restrict__ W,
               float* __restrict__ V,
               float* __restrict__ PL, float* __restrict__ PR,
               int4* __restrict__ ROWS, int* __restrict__ PROW,
               float* __restrict__ H, float* __restrict__ Cc,
               float* __restrict__ CH, float* __restrict__ CC,
               float* __restrict__ LG, int* __restrict__ NXT,
               int* __restrict__ PRV,
               const float* __restrict__ bias, const float* __restrict__ q,
               unsigned int* __restrict__ FG, unsigned int* __restrict__ FC)
{
    constexpr int MI = 4, KT = 16;
    constexpr int LDA = 68, LDB = 68;
    __shared__ float As[2][16*LDA];
    __shared__ float Bs[2][16*LDB];
    __shared__ float red[4];
    __shared__ int ss[1];

    const int bid = blockIdx.x;
    const int t = threadIdx.x;
    const unsigned ui = (unsigned)i;

    // ===== Stage G: GEMM tile =====
    {
        const int mx = bid & 1;
        const int kz = (bid >> 1) & 1;
        const int ny = bid >> 2;              // 0..79
        const int side = (ny >= 40);
        const int n0 = (ny - 40*side)*64;
        const int m0 = mx*64;
        const int kg0 = kz*KT*16;

        const int arow = t >> 2, aseg = t & 3;
        const float* aptr = H + (size_t)PROW[m0 + arow]*HID + aseg*4 + kg0;
        const float* bptr = W + (size_t)(n0 + arow)*1024 + side*HID + aseg*4 + kg0;

        const int tm = t >> 4, tn = t & 15;

        float acc[MI][4];
        #pragma unroll
        for (int mi=0;mi<MI;++mi)
            #pragma unroll
            for (int j=0;j<4;++j) acc[mi][j]=0.f;

        float4 av, bv;
        auto gload = [&](int kt){
            av = *(const float4*)(aptr + kt*16);
            bv = *(const float4*)(bptr + kt*16);
        };
        auto swrite = [&](int buf){
            As[buf][(aseg*4+0)*LDA + arow] = av.x;
            As[buf][(aseg*4+1)*LDA + arow] = av.y;
            As[buf][(aseg*4+2)*LDA + arow] = av.z;
            As[buf][(aseg*4+3)*LDA + arow] = av.w;
            Bs[buf][(aseg*4+0)*LDB + arow] = bv.x;
            Bs[buf][(aseg*4+1)*LDB + arow] = bv.y;
            Bs[buf][(aseg*4+2)*LDB + arow] = bv.z;
            Bs[buf][(aseg*4+3)*LDB + arow] = bv.w;
        };

        gload(0); swrite(0); __syncthreads();

        for (int kt=0; kt<KT; ++kt){
            int buf = kt & 1;
            if (kt+1 < KT) gload(kt+1);
            #pragma unroll
            for (int k=0;k<16;++k){
                float4 a4 = *(const float4*)&As[buf][k*LDA + tm*MI];
                float4 b4 = *(const float4*)&Bs[buf][k*LDB + tn*4];
                float a[4] = {a4.x,a4.y,a4.z,a4.w};
                #pragma unroll
                for (int mi=0;mi<MI;++mi){
                    acc[mi][0] = fmaf(a[mi], b4.x, acc[mi][0]);
                    acc[mi][1] = fmaf(a[mi], b4.y, acc[mi][1]);
                    acc[mi][2] = fmaf(a[mi], b4.z, acc[mi][2]);
                    acc[mi][3] = fmaf(a[mi], b4.w, acc[mi][3]);
                }
            }
            if (kt+1 < KT) swrite(buf^1);
            __syncthreads();
        }

        #pragma unroll
        for (int mi=0;mi<MI;++mi){
            int row = m0 + tm*MI + mi;       // = batch index
            float4 o; o.x=acc[mi][0]; o.y=acc[mi][1]; o.z=acc[mi][2]; o.w=acc[mi][3];
            *(float4*)(V + ((size_t)(kz*2+side)*NB + row)*NN + n0 + tn*4) = o;
        }

        __threadfence();
        __syncthreads();
        if (t == 0)
            __hip_atomic_store(&FG[bid], ui, __ATOMIC_RELEASE, __HIP_MEMORY_SCOPE_AGENT);
    }

    if (bid >= 256) return;

    // ===== Stage C1: per-(batch,pair) combine =====
    {
        const int b = bid >> 1, e = bid & 1;
        const int base = b*NSLOT;
        const int sideR = e ^ 1;             // e=0 reads PR-side partials, e=1 PL-side
        const int mx = b >> 6;
        // wave 0 polls the 80 producer flags (ny in side range, kz in {0,1}, mx fixed)
        if (t < 64){
            auto gidOf = [&](int x){           // x = kz*40 + j, x in [0,80)
                int kz = (x >= 40); int j = x - kz*40;
                return (sideR*40 + j)*4 + kz*2 + mx;
            };
            int g1 = gidOf(t);
            int g2 = (t < 16) ? gidOf(64 + t) : g1;
            for (;;){
                unsigned v1 = __hip_atomic_load(&FG[g1], __ATOMIC_ACQUIRE, __HIP_MEMORY_SCOPE_AGENT);
                unsigned v2 = (t < 16) ? __hip_atomic_load(&FG[g2], __ATOMIC_ACQUIRE, __HIP_MEMORY_SCOPE_AGENT) : ui;
                if (__all(v1 == ui && v2 == ui)) break;
                __builtin_amdgcn_s_sleep(2);
            }
        }
        __syncthreads();

        int4 rd = ROWS[b*2+e];
        bool valid = (rd.w >= 0);
        int node = PROW[b];
        float* CACHE = (e == 0) ? PR : PL;

        float vnew[10];
        #pragma unroll
        for (int jj=0;jj<10;++jj){
            int c = jj*256 + t;
            vnew[jj] = V[((size_t)(0+sideR)*NB + b)*NN + c]
                     + V[((size_t)(2+sideR)*NB + b)*NN + c];
            CACHE[(size_t)node*NN + c] = vnew[jj];
        }

        float part = 0.f;
        if (valid){
            const float* OTH = e ? (PR + (size_t)(base+rd.z)*NN)
                                 : (PL + (size_t)(base+rd.y)*NN);
            const float* cl = Cc + (size_t)(base+rd.y)*HID;
            const float* cr = Cc + (size_t)(base+rd.z)*HID;
            int dst = rd.w;
            #pragma unroll
            for (int h2=0; h2<2; ++h2){
                int c = t + h2*256;
                float v[5];
                #pragma unroll
                for (int g=0; g<5; ++g)
                    v[g] = OTH[g*HID + c] + vnew[g*2+h2] + bias[g*HID + c];
                float cn = cl[c]*sigf(v[1]+1.f) + cr[c]*sigf(v[2]+1.f) + tanhf(v[3])*sigf(v[0]);
                float hn = sigf(v[4])*tanhf(cn);
                CH[(size_t)(base+dst)*HID + c] = hn;
                CC[(size_t)(base+dst)*HID + c] = cn;
                part += q[c]*hn;
            }
        }
        #pragma unroll
        for (int off=32; off; off>>=1) part += __shfl_xor(part, off);
        if ((t & 63) == 0) red[t>>6] = part;
        __syncthreads();
        if (t == 0 && valid)
            LG[base + rd.w] = red[0]+red[1]+red[2]+red[3];

        __threadfence();
        __syncthreads();
        if (t == 0)
            __hip_atomic_store(&FC[b*2+e], ui, __ATOMIC_RELEASE, __HIP_MEMORY_SCOPE_AGENT);
    }

    if (bid >= 128) return;

    // ===== Stage C2: per-batch argmax + commit + relink =====
    {
        const int b = bid;
        const int base = b*NSLOT;
        if (t < 64){
            for (;;){
                unsigned v = (t < 2) ? __hip_atomic_load(&FC[b*2+t], __ATOMIC_ACQUIRE, __HIP_MEMORY_SCOPE_AGENT) : ui;
                if (__all(v == ui)) break;
                __builtin_amdgcn_s_sleep(2);
            }
        }
        __syncthreads();

        int lb = len[b];
        if (i > lb-2){
            if (t==0){
                ROWS[b*2+0]=make_int4(0,0,0,-1);
                ROWS[b*2+1]=make_int4(0,0,0,-1);
                PROW[b]=base;
            }
            return;
        }

        if (t < 64){
            float val = (t < NSLOT)? LG[base+t] : -FLT_MAX;
            int idx = t;
            for (int off=1; off<64; off<<=1){
                float ov=__shfl_xor(val,off); int oi=__shfl_xor(idx,off);
                if (ov>val || (ov==val && oi<idx)){ val=ov; idx=oi; }
            }
            if (t==0) ss[0]=idx;
        }
        __syncthreads();
        int sstar = ss[0];
        {
            const float4* sh = (const float4*)(CH + (size_t)(base+sstar)*HID);
            const float4* sc = (const float4*)(CC + (size_t)(base+sstar)*HID);
            float4* dh = (float4*)(H  + (size_t)(base+sstar)*HID);
            float4* dc = (float4*)(Cc + (size_t)(base+sstar)*HID);
            if (t < 128) dh[t] = sh[t];
            else         dc[t-128] = sc[t-128];
        }
        if (t == 0){
            int r  = NXT[base+sstar];
            int qn = NXT[base+r];
            int p  = PRV[base+sstar];
            NXT[base+sstar] = qn;
            if (qn >= 0) PRV[base+qn] = sstar;
            LG[base+r] = -FLT_MAX;
            if (qn < 0) LG[base+sstar] = -FLT_MAX;
            ROWS[b*2+0] = (p  >= 0) ? make_int4(b, p, sstar, p)      : make_int4(0,0,0,-1);
            ROWS[b*2+1] = (qn >= 0) ? make_int4(b, sstar, qn, sstar) : make_int4(0,0,0,-1);
            PROW[b] = base + sstar;
        }
    }
}

// ---------------- output: root = slot 0 ----------------
__global__ void k_out(const float* __restrict__ H, float* __restrict__ out)
{
    int b = blockIdx.x, t = threadIdx.x;       // 128 threads x float4
    ((float4*)out)[b*128 + t] = ((const float4*)(H + (size_t)b*NSLOT*HID))[t];
}

extern "C" void kernel_launch(void* const* d_in, const int* in_sizes, int n_in,
                              void* d_out, int out_size, void* d_ws, size_t ws_size,
                              hipStream_t stream)
{
    const float* in   = (const float*)d_in[0];
    const float* W    = (const float*)d_in[1];
    const float* bias = (const float*)d_in[2];
    const float* q    = (const float*)d_in[3];
    const int*   len  = (const int*)d_in[4];

    float* ws = (float*)d_ws;
    float* H  = ws + offH;
    float* Cc = ws + offC;
    float* CH = ws + offCH;
    float* CC = ws + offCC;
    float* LG = ws + offLG;
    int* NXT  = (int*)(ws + offNXT);
    int* PRV  = (int*)(ws + offPRV);
    int4* ROWS  = (int4*)(ws + offROWS);
    int4* ROWSA = (int4*)(ws + offROWSA);
    int*  ROWSN = (int*)(ws + offROWSN);
    int*  PROW  = (int*)(ws + offPROW);
    int*  NLIVE = (int*)(ws + offNLIV);
    unsigned int* FG = (unsigned int*)(ws + offFG);
    unsigned int* FC = (unsigned int*)(ws + offFC);
    float* V  = ws + offV;
    float* PL = ws + offBIG;
    float* PR = PL + (size_t)NNODE*NN;
    float* out = (float*)d_out;

    k_init <<<dim3(NNODE), dim3(256), 0, stream>>>(in, len, H, Cc, LG, NXT, PRV, ROWS);
    k_descA<<<dim3(1), dim3(256), 0, stream>>>(len, ROWSA, ROWSN, NLIVE, FG, FC);

    // phase A: per-node products (compacted rows) + pair combine + first merge
    k_gemmP<8,32><<<dim3(NNODE/128, 2*NN/64), dim3(256), 0, stream>>>(ROWSN, NLIVE, H, W, PL, PR);
    k_combineP<<<dim3(AROWS), dim3(256), 0, stream>>>(ROWSA, PL, PR, Cc, bias, q, CH, CC, LG);
    k_step0<<<dim3(NB), dim3(64), 0, stream>>>(len, H, Cc, CH, CC, LG, NXT, PRV, ROWS, PROW);

    // step loop: ONE fused kernel per iteration, flag-based internal barriers
    for (int i = 1; i < NL-1; ++i){
        k_stepOne<<<dim3(320), dim3(256), 0, stream>>>(
            i, len, W, V, PL, PR, ROWS, PROW, H, Cc, CH, CC, LG, NXT, PRV,
            bias, q, FG, FC);
    }
    k_out<<<dim3(NB), dim3(128), 0, stream>>>(H, out);
}

// Round 11
// 1447.026 us; speedup vs baseline: 4.5044x; 4.3589x over previous
//
#include <hip/hip_runtime.h>
#include <cfloat>
#include <cmath>

#define NB 128
#define NL 48
#define HID 512
#define NSLOT 48
#define NN 2560              // 5*HID output cols
#define NNODE (NB*NSLOT)     // 6144
#define AROWS (NB*(NL-1))    // 6016 phase-A pair rows

// ---------------- workspace layout (float units) ----------------
static const size_t offH    = 0;                                   // [B][48][512]
static const size_t offC    = offH  + (size_t)NNODE*HID;
static const size_t offCH   = offC  + (size_t)NNODE*HID;           // candidate h
static const size_t offCC   = offCH + (size_t)NNODE*HID;           // candidate c
static const size_t offLG   = offCC + (size_t)NNODE*HID;           // logits [B][48]
static const size_t offNXT  = offLG  + NNODE;                      // int
static const size_t offPRV  = offNXT + NNODE;                      // int
static const size_t offROWS = offPRV + NNODE;                      // int4 x 256
static const size_t offROWSA= offROWS + (size_t)4*(2*NB);          // int4 x 6016
static const size_t offROWSN= offROWSA + (size_t)4*AROWS;          // int x 6144 (compacted)
static const size_t offPROW = offROWSN + NNODE;                    // int x 128
static const size_t offNLIV = offPROW + 128;                       // int x 1 (+pad)
static const size_t offV    = offNLIV + 32;                        // V partials, then PL/PR
// KS=2: V = 4*NB*NN (5.2MB) -> total 181.6 MB (proven, round 10 ran it)
// KS=4: V = 8*NB*NN (10.5MB) -> total 186.8 MB (gated on ws_size)

__device__ __forceinline__ float sigf(float x){ return 1.0f/(1.0f+expf(-x)); }

// ---------------- init: copy input -> H,C ; init links/logits ----------------
__global__ void k_init(const float* __restrict__ in, const int* __restrict__ len,
                       float* __restrict__ H, float* __restrict__ Cc,
                       float* __restrict__ LG, int* __restrict__ NXT,
                       int* __restrict__ PRV, int4* __restrict__ ROWS)
{
    int bs = blockIdx.x;            // b*48+s
    int b  = bs / NSLOT, s = bs % NSLOT;
    int t  = threadIdx.x;           // 256 threads, 1 float4 each
    const float4* inrow = (const float4*)(in + (size_t)bs*2*HID);
    float4 v = inrow[t];
    if (t < 128) ((float4*)(H  + (size_t)bs*HID))[t]       = v;
    else         ((float4*)(Cc + (size_t)bs*HID))[t - 128] = v;
    if (t == 0) {
        int lb = len[b];
        NXT[bs] = (s+1 < lb) ? s+1 : -1;
        PRV[bs] = (s > 0 && s < lb) ? s-1 : -1;
        LG[bs]  = -FLT_MAX;
        if (s == 0) {
            ROWS[b*2+0] = make_int4(0,0,0,-1);
            ROWS[b*2+1] = make_int4(0,0,0,-1);
        }
    }
}

// ---------------- descriptors: pair rows + COMPACTED live node rows ----------------
__global__ void k_descA(const int* __restrict__ len, int4* __restrict__ ROWSA,
                        int* __restrict__ ROWSN, int* __restrict__ NLIVE)
{
    __shared__ int off[NB+1];
    int t = threadIdx.x;            // single block, 256 threads
    if (t == 0){
        int acc = 0;
        for (int b=0;b<NB;++b){ off[b]=acc; acc += len[b]; }
        off[NB] = acc;
        NLIVE[0] = (acc + 127) & ~127;
    }
    __syncthreads();
    int nlive = off[NB];
    int npad  = (nlive + 127) & ~127;
    for (int r = t; r < AROWS; r += 256){
        int b = r/(NL-1), s = r%(NL-1);
        int lb = len[b];
        ROWSA[r] = make_int4(b, s, s+1, (s <= lb-2) ? s : -1);
    }
    for (int x = t; x < NNODE; x += 256){
        int b = x / NSLOT, s = x % NSLOT;
        if (s < len[b]) ROWSN[off[b] + s] = x;
    }
    for (int x = nlive + t; x < npad; x += 256) ROWSN[x] = 0;
}

// ================= phase-A split-W product GEMM (8x4 micro, 6 blocks/CU) =================
// PL[node][n] = sum_k H[node][k]*W[n][k],  PR[node][n] = sum_k H[node][k]*W[n][512+k]
template<int MI, int KT>
__global__ __launch_bounds__(256, 6)
void k_gemmP(const int* __restrict__ rows, const int* __restrict__ NLIVE,
             const float* __restrict__ H, const float* __restrict__ W,
             float* __restrict__ PL, float* __restrict__ PR)
{
    constexpr int BM  = 16*MI;
    constexpr int AF4 = BM/64;
    constexpr int LDA = BM + 4;
    constexpr int LDB = 68;

    const int m0  = blockIdx.x*BM;
    if (m0 >= NLIVE[0]) return;     // compacted: skip dead tiles

    __shared__ float As[2][16*LDA];
    __shared__ float Bs[2][16*LDB];

    const int t   = threadIdx.x;
    const int vn0 = blockIdx.y*64;
    const int side = (vn0 >= NN);
    const int n0  = side ? vn0 - NN : vn0;
    float* OUT = side ? PR : PL;

    int aoff[AF4], arow[AF4], aseg[AF4];
    #pragma unroll
    for (int j=0;j<AF4;++j){
        int f = t*AF4 + j;
        arow[j] = f >> 2; aseg[j] = f & 3;
        aoff[j] = rows[m0 + arow[j]]*HID + aseg[j]*4;
    }
    const int brow = t >> 2, bseg = t & 3;
    const float* wptr = W + (size_t)(n0 + brow)*1024 + side*HID + bseg*4;

    const int tm = t >> 4, tn = t & 15;

    float acc[MI][4];
    #pragma unroll
    for (int mi=0;mi<MI;++mi)
        #pragma unroll
        for (int j=0;j<4;++j) acc[mi][j]=0.f;

    float4 av[AF4], bv;
    auto gload = [&](int kt){
        int kg = kt*16;
        #pragma unroll
        for (int j=0;j<AF4;++j) av[j] = *(const float4*)(H + aoff[j] + kg);
        bv = *(const float4*)(wptr + kg);
    };
    auto swrite = [&](int buf){
        #pragma unroll
        for (int j=0;j<AF4;++j){
            As[buf][(aseg[j]*4+0)*LDA + arow[j]] = av[j].x;
            As[buf][(aseg[j]*4+1)*LDA + arow[j]] = av[j].y;
            As[buf][(aseg[j]*4+2)*LDA + arow[j]] = av[j].z;
            As[buf][(aseg[j]*4+3)*LDA + arow[j]] = av[j].w;
        }
        Bs[buf][(bseg*4+0)*LDB + brow] = bv.x;
        Bs[buf][(bseg*4+1)*LDB + brow] = bv.y;
        Bs[buf][(bseg*4+2)*LDB + brow] = bv.z;
        Bs[buf][(bseg*4+3)*LDB + brow] = bv.w;
    };

    gload(0); swrite(0); __syncthreads();

    for (int kt=0; kt<KT; ++kt){
        int buf = kt & 1;
        if (kt+1 < KT) gload(kt+1);
        #pragma unroll
        for (int k=0;k<16;++k){
            float a[MI];
            #pragma unroll
            for (int mi=0;mi<MI;mi+=4){
                float4 a4 = *(const float4*)&As[buf][k*LDA + tm*MI + mi];
                a[mi]=a4.x; a[mi+1]=a4.y; a[mi+2]=a4.z; a[mi+3]=a4.w;
            }
            float4 b4 = *(const float4*)&Bs[buf][k*LDB + tn*4];
            #pragma unroll
            for (int mi=0;mi<MI;++mi){
                acc[mi][0] = fmaf(a[mi], b4.x, acc[mi][0]);
                acc[mi][1] = fmaf(a[mi], b4.y, acc[mi][1]);
                acc[mi][2] = fmaf(a[mi], b4.z, acc[mi][2]);
                acc[mi][3] = fmaf(a[mi], b4.w, acc[mi][3]);
            }
        }
        if (kt+1 < KT) swrite(buf^1);
        __syncthreads();
    }

    #pragma unroll
    for (int mi=0;mi<MI;++mi){
        int row = m0 + tm*MI + mi;
        float4 o; o.x=acc[mi][0]; o.y=acc[mi][1]; o.z=acc[mi][2]; o.w=acc[mi][3];
        *(float4*)(OUT + (size_t)rows[row]*NN + n0 + tn*4) = o;
    }
}

// ================= step GEMM: K-split -> V partials =================
// grid (2, 80, KS): BM=64, BN=64, 4x4 micro, K=512/KS per kz.
// V[((kz*2+side)*NB + row)*NN + n] = partial.
template<int KS>
__global__ __launch_bounds__(256, 4)
void k_gemmV(const int* __restrict__ rows,
             const float* __restrict__ H, const float* __restrict__ W,
             float* __restrict__ V)
{
    constexpr int MI = 4, KT = 32/KS;
    constexpr int LDA = 68;
    constexpr int LDB = 68;
    __shared__ float As[2][16*LDA];
    __shared__ float Bs[2][16*LDB];

    const int t   = threadIdx.x;
    const int m0  = blockIdx.x*64;
    const int vn0 = blockIdx.y*64;
    const int side = (vn0 >= NN);
    const int n0  = side ? vn0 - NN : vn0;
    const int kz  = blockIdx.z;
    const int kg0 = kz*KT*16;

    const int arow = t >> 2, aseg = t & 3;
    const float* aptr = H + (size_t)rows[m0 + arow]*HID + aseg*4 + kg0;
    const float* bptr = W + (size_t)(n0 + arow)*1024 + side*HID + aseg*4 + kg0;

    const int tm = t >> 4, tn = t & 15;

    float acc[MI][4];
    #pragma unroll
    for (int mi=0;mi<MI;++mi)
        #pragma unroll
        for (int j=0;j<4;++j) acc[mi][j]=0.f;

    float4 av, bv;
    auto gload = [&](int kt){
        av = *(const float4*)(aptr + kt*16);
        bv = *(const float4*)(bptr + kt*16);
    };
    auto swrite = [&](int buf){
        As[buf][(aseg*4+0)*LDA + arow] = av.x;
        As[buf][(aseg*4+1)*LDA + arow] = av.y;
        As[buf][(aseg*4+2)*LDA + arow] = av.z;
        As[buf][(aseg*4+3)*LDA + arow] = av.w;
        Bs[buf][(aseg*4+0)*LDB + arow] = bv.x;
        Bs[buf][(aseg*4+1)*LDB + arow] = bv.y;
        Bs[buf][(aseg*4+2)*LDB + arow] = bv.z;
        Bs[buf][(aseg*4+3)*LDB + arow] = bv.w;
    };

    gload(0); swrite(0); __syncthreads();

    for (int kt=0; kt<KT; ++kt){
        int buf = kt & 1;
        if (kt+1 < KT) gload(kt+1);
        #pragma unroll
        for (int k=0;k<16;++k){
            float4 a4 = *(const float4*)&As[buf][k*LDA + tm*MI];
            float4 b4 = *(const float4*)&Bs[buf][k*LDB + tn*4];
            float a[4] = {a4.x,a4.y,a4.z,a4.w};
            #pragma unroll
            for (int mi=0;mi<MI;++mi){
                acc[mi][0] = fmaf(a[mi], b4.x, acc[mi][0]);
                acc[mi][1] = fmaf(a[mi], b4.y, acc[mi][1]);
                acc[mi][2] = fmaf(a[mi], b4.z, acc[mi][2]);
                acc[mi][3] = fmaf(a[mi], b4.w, acc[mi][3]);
            }
        }
        if (kt+1 < KT) swrite(buf^1);
        __syncthreads();
    }

    #pragma unroll
    for (int mi=0;mi<MI;++mi){
        int row = m0 + tm*MI + mi;      // = batch index (M = NB)
        float4 o; o.x=acc[mi][0]; o.y=acc[mi][1]; o.z=acc[mi][2]; o.w=acc[mi][3];
        *(float4*)(V + ((size_t)(kz*2+side)*NB + row)*NN + n0 + tn*4) = o;
    }
}

// ---------------- phase-A combine: v = PL[l]+PR[r]+bias -> gates -> CH/CC + logit ----------------
__global__ void k_combineP(const int4* __restrict__ rows,
                           const float* __restrict__ PL, const float* __restrict__ PR,
                           const float* __restrict__ Cc, const float* __restrict__ bias,
                           const float* __restrict__ q,
                           float* __restrict__ CH, float* __restrict__ CC,
                           float* __restrict__ LG)
{
    int4 rd = rows[blockIdx.x];
    if (rd.w < 0) return;
    int t = threadIdx.x;
    int b = rd.x, sl = rd.y, sr = rd.z, dst = rd.w;
    const float* pl = PL + (size_t)(b*NSLOT+sl)*NN;
    const float* pr = PR + (size_t)(b*NSLOT+sr)*NN;
    const float* cl = Cc + (size_t)(b*NSLOT+sl)*HID;
    const float* cr = Cc + (size_t)(b*NSLOT+sr)*HID;
    float part = 0.f;
    #pragma unroll
    for (int h2=0; h2<2; ++h2){
        int c = t + h2*256;
        float v[5];
        #pragma unroll
        for (int g=0; g<5; ++g)
            v[g] = pl[g*HID+c] + pr[g*HID+c] + bias[g*HID+c];
        float cn = cl[c]*sigf(v[1]+1.f) + cr[c]*sigf(v[2]+1.f) + tanhf(v[3])*sigf(v[0]);
        float hn = sigf(v[4])*tanhf(cn);
        CH[(size_t)(b*NSLOT+dst)*HID + c] = hn;
        CC[(size_t)(b*NSLOT+dst)*HID + c] = cn;
        part += q[c]*hn;
    }
    __shared__ float red[4];
    #pragma unroll
    for (int off=32; off; off>>=1) part += __shfl_xor(part, off);
    if ((t & 63) == 0) red[t>>6] = part;
    __syncthreads();
    if (t == 0) LG[b*NSLOT + dst] = red[0]+red[1]+red[2]+red[3];
}

// ---------------- step 0: argmax, commit, relink (phase-A logits) ----------------
__global__ void k_step0(const int* __restrict__ len,
                        float* __restrict__ H, float* __restrict__ Cc,
                        const float* __restrict__ CH, const float* __restrict__ CC,
                        float* __restrict__ LG, int* __restrict__ NXT,
                        int* __restrict__ PRV, int4* __restrict__ ROWS,
                        int* __restrict__ PROW)
{
    int b = blockIdx.x, lane = threadIdx.x;   // block = 64 = 1 wave
    int base = b*NSLOT;

    float val = (lane < NSLOT) ? LG[base+lane] : -FLT_MAX;
    int idx = lane;
    for (int off=1; off<64; off<<=1){
        float oval = __shfl_xor(val, off);
        int   oidx = __shfl_xor(idx, off);
        if (oval > val || (oval == val && oidx < idx)){ val = oval; idx = oidx; }
    }
    int sstar = idx;
    int r  = NXT[base+sstar];
    int qn = NXT[base+r];
    int p  = PRV[base+sstar];

    const float4* sh = (const float4*)(CH + (size_t)(base+sstar)*HID);
    const float4* sc = (const float4*)(CC + (size_t)(base+sstar)*HID);
    float4* dh = (float4*)(H  + (size_t)(base+sstar)*HID);
    float4* dc = (float4*)(Cc + (size_t)(base+sstar)*HID);
    dh[lane] = sh[lane]; dh[lane+64] = sh[lane+64];
    dc[lane] = sc[lane]; dc[lane+64] = sc[lane+64];

    if (lane==0){
        NXT[base+sstar] = qn;
        if (qn >= 0) PRV[base+qn] = sstar;
        LG[base+r] = -FLT_MAX;
        if (qn < 0) LG[base+sstar] = -FLT_MAX;
        ROWS[b*2+0] = (p  >= 0) ? make_int4(b, p, sstar, p)      : make_int4(0,0,0,-1);
        ROWS[b*2+1] = (qn >= 0) ? make_int4(b, sstar, qn, sstar) : make_int4(0,0,0,-1);
        PROW[b] = base + sstar;
    }
}

// ---------------- fused combine+step: 512 threads, pairs in parallel ----------------
// threads 0-255: pair 0 (p,new) needs PRnew (side 1); 256-511: pair 1 (new,qn) needs PLnew (side 0).
template<int KS>
__global__ __launch_bounds__(512, 2)
void k_combineStep(int i, const int* __restrict__ len,
                   const float* __restrict__ V,
                   float* __restrict__ PL, float* __restrict__ PR,
                   int4* __restrict__ ROWS, int* __restrict__ PROW,
                   float* __restrict__ H, float* __restrict__ Cc,
                   float* __restrict__ CH, float* __restrict__ CC,
                   float* __restrict__ LG, int* __restrict__ NXT,
                   int* __restrict__ PRV,
                   const float* __restrict__ bias, const float* __restrict__ q)
{
    int b = blockIdx.x, t = threadIdx.x;
    int base = b*NSLOT;
    int e = t >> 8, u = t & 255;
    int4 rd = ROWS[b*2+e];
    bool valid = (rd.w >= 0);
    int node = PROW[b];
    __shared__ float slg[NSLOT];
    __shared__ float red[8];
    __shared__ int ss[1];

    // sum V partials for my side; write-through to cache
    int side = (e == 0) ? 1 : 0;
    float* CACHE = (e == 0) ? PR : PL;
    float vnew[10];
    #pragma unroll
    for (int jj=0;jj<10;++jj){
        int c = jj*256 + u;
        float s = 0.f;
        #pragma unroll
        for (int kz=0; kz<KS; ++kz)
            s += V[((size_t)(kz*2+side)*NB + b)*NN + c];
        vnew[jj] = s;
        CACHE[(size_t)node*NN + c] = s;
    }

    float part = 0.f;
    if (valid){
        const float* OTH = e ? (PR + (size_t)(base+rd.z)*NN)
                             : (PL + (size_t)(base+rd.y)*NN);
        const float* cl = Cc + (size_t)(base+rd.y)*HID;
        const float* cr = Cc + (size_t)(base+rd.z)*HID;
        int dst = rd.w;
        #pragma unroll
        for (int h2=0; h2<2; ++h2){
            int c = u + h2*256;
            float v[5];
            #pragma unroll
            for (int g=0; g<5; ++g)
                v[g] = OTH[g*HID + c] + vnew[g*2+h2] + bias[g*HID + c];
            float cn = cl[c]*sigf(v[1]+1.f) + cr[c]*sigf(v[2]+1.f) + tanhf(v[3])*sigf(v[0]);
            float hn = sigf(v[4])*tanhf(cn);
            CH[(size_t)(base+dst)*HID + c] = hn;
            CC[(size_t)(base+dst)*HID + c] = cn;
            part += q[c]*hn;
        }
    }
    #pragma unroll
    for (int off=32; off; off>>=1) part += __shfl_xor(part, off);
    if ((t & 63) == 0) red[t>>6] = part;
    if (t < NSLOT) slg[t] = LG[base+t];
    __syncthreads();

    if (t == 0){
        int4 r1 = ROWS[b*2+1];
        float s0 = red[0]+red[1]+red[2]+red[3];
        float s1 = red[4]+red[5]+red[6]+red[7];
        if (rd.w >= 0){ LG[base+rd.w]=s0; slg[rd.w]=s0; }      // pair 0 (t==0 has e=0)
        if (r1.w >= 0){ LG[base+r1.w]=s1; slg[r1.w]=s1; }
    }
    __syncthreads();

    int lb = len[b];
    if (i > lb-2){
        if (t==0){
            ROWS[b*2+0]=make_int4(0,0,0,-1);
            ROWS[b*2+1]=make_int4(0,0,0,-1);
            PROW[b]=base;
        }
        return;
    }

    if (t < 64){
        float val = (t < NSLOT)? slg[t] : -FLT_MAX;
        int idx = t;
        for (int off=1; off<64; off<<=1){
            float ov=__shfl_xor(val,off); int oi=__shfl_xor(idx,off);
            if (ov>val || (ov==val && oi<idx)){ val=ov; idx=oi; }
        }
        if (t==0) ss[0]=idx;
    }
    __syncthreads();
    int sstar = ss[0];
    {
        const float4* sh = (const float4*)(CH + (size_t)(base+sstar)*HID);
        const float4* sc = (const float4*)(CC + (size_t)(base+sstar)*HID);
        float4* dh = (float4*)(H  + (size_t)(base+sstar)*HID);
        float4* dc = (float4*)(Cc + (size_t)(base+sstar)*HID);
        if (t < 128)      dh[t] = sh[t];
        else if (t < 256) dc[t-128] = sc[t-128];
    }
    if (t == 0){
        int r  = NXT[base+sstar];
        int qn = NXT[base+r];
        int p  = PRV[base+sstar];
        NXT[base+sstar] = qn;
        if (qn >= 0) PRV[base+qn] = sstar;
        LG[base+r] = -FLT_MAX;
        if (qn < 0) LG[base+sstar] = -FLT_MAX;
        ROWS[b*2+0] = (p  >= 0) ? make_int4(b, p, sstar, p)      : make_int4(0,0,0,-1);
        ROWS[b*2+1] = (qn >= 0) ? make_int4(b, sstar, qn, sstar) : make_int4(0,0,0,-1);
        PROW[b] = base + sstar;
    }
}

// ---------------- output: root = slot 0 ----------------
__global__ void k_out(const float* __restrict__ H, float* __restrict__ out)
{
    int b = blockIdx.x, t = threadIdx.x;       // 128 threads x float4
    ((float4*)out)[b*128 + t] = ((const float4*)(H + (size_t)b*NSLOT*HID))[t];
}

extern "C" void kernel_launch(void* const* d_in, const int* in_sizes, int n_in,
                              void* d_out, int out_size, void* d_ws, size_t ws_size,
                              hipStream_t stream)
{
    const float* in   = (const float*)d_in[0];
    const float* W    = (const float*)d_in[1];
    const float* bias = (const float*)d_in[2];
    const float* q    = (const float*)d_in[3];
    const int*   len  = (const int*)d_in[4];

    float* ws = (float*)d_ws;
    float* H  = ws + offH;
    float* Cc = ws + offC;
    float* CH = ws + offCH;
    float* CC = ws + offCC;
    float* LG = ws + offLG;
    int* NXT  = (int*)(ws + offNXT);
    int* PRV  = (int*)(ws + offPRV);
    int4* ROWS  = (int4*)(ws + offROWS);
    int4* ROWSA = (int4*)(ws + offROWSA);
    int*  ROWSN = (int*)(ws + offROWSN);
    int*  PROW  = (int*)(ws + offPROW);
    int*  NLIVE = (int*)(ws + offNLIV);
    float* V  = ws + offV;
    float* out = (float*)d_out;

    // choose K-split by available workspace
    const size_t vsz2 = (size_t)4*NB*NN;
    const size_t vsz4 = (size_t)8*NB*NN;
    const size_t plprsz = (size_t)2*NNODE*NN;
    const bool ks4 = (ws_size >= (offV + vsz4 + plprsz)*sizeof(float));
    float* PL = ws + offV + (ks4 ? vsz4 : vsz2);
    float* PR = PL + (size_t)NNODE*NN;

    k_init <<<dim3(NNODE), dim3(256), 0, stream>>>(in, len, H, Cc, LG, NXT, PRV, ROWS);
    k_descA<<<dim3(1), dim3(256), 0, stream>>>(len, ROWSA, ROWSN, NLIVE);

    // phase A: per-node products (compacted rows, 6 blocks/CU) + pair combine + first merge
    k_gemmP<8,32><<<dim3(NNODE/128, 2*NN/64), dim3(256), 0, stream>>>(ROWSN, NLIVE, H, W, PL, PR);
    k_combineP<<<dim3(AROWS), dim3(256), 0, stream>>>(ROWSA, PL, PR, Cc, bias, q, CH, CC, LG);
    k_step0<<<dim3(NB), dim3(64), 0, stream>>>(len, H, Cc, CH, CC, LG, NXT, PRV, ROWS, PROW);

    // step loop: 2 kernels per iteration
    if (ks4){
        for (int i = 1; i < NL-1; ++i){
            k_gemmV<4><<<dim3(2, 2*NN/64, 4), dim3(256), 0, stream>>>(PROW, H, W, V);
            k_combineStep<4><<<dim3(NB), dim3(512), 0, stream>>>(
                i, len, V, PL, PR, ROWS, PROW, H, Cc, CH, CC, LG, NXT, PRV, bias, q);
        }
    } else {
        for (int i = 1; i < NL-1; ++i){
            k_gemmV<2><<<dim3(2, 2*NN/64, 2), dim3(256), 0, stream>>>(PROW, H, W, V);
            k_combineStep<2><<<dim3(NB), dim3(512), 0, stream>>>(
                i, len, V, PL, PR, ROWS, PROW, H, Cc, CH, CC, LG, NXT, PRV, bias, q);
        }
    }
    k_out<<<dim3(NB), dim3(128), 0, stream>>>(H, out);
}

// Round 12
// 1441.384 us; speedup vs baseline: 4.5220x; 1.0039x over previous
//
#include <hip/hip_runtime.h>
#include <cfloat>
#include <cmath>

#define NB 128
#define NL 48
#define HID 512
#define NSLOT 48
#define NN 2560              // 5*HID output cols
#define NNODE (NB*NSLOT)     // 6144
#define AROWS (NB*(NL-1))    // 6016 phase-A pair rows

// ---------------- workspace layout (float units) ----------------
static const size_t offH    = 0;                                   // [B][48][512]
static const size_t offC    = offH  + (size_t)NNODE*HID;
static const size_t offCH   = offC  + (size_t)NNODE*HID;           // candidate h
static const size_t offCC   = offCH + (size_t)NNODE*HID;           // candidate c
static const size_t offLG   = offCC + (size_t)NNODE*HID;           // logits [B][48]
static const size_t offNXT  = offLG  + NNODE;                      // int
static const size_t offPRV  = offNXT + NNODE;                      // int
static const size_t offROWS = offPRV + NNODE;                      // int4 x 256
static const size_t offROWSA= offROWS + (size_t)4*(2*NB);          // int4 x 6016
static const size_t offROWSN= offROWSA + (size_t)4*AROWS;          // int x 6144 (compacted)
static const size_t offPROW = offROWSN + NNODE;                    // int x 128
static const size_t offNLIV = offPROW + 128;                       // int x 1 (+pad)
static const size_t offPOSB = offNLIV + 32;                        // int x 128
static const size_t offNACT = offPOSB + 128;                       // int x 64 (per-iter active count)
static const size_t offPRWC = offNACT + 64;                        // int x 47*128 (compacted rows)
static const size_t offV    = offPRWC + 6016;                      // V partials, then PL/PR
// KS=4: V = 8*NB*NN (10.5MB) -> total ~186.9 MB (gated on ws_size; proven in round 11)

__device__ __forceinline__ float sigf(float x){ return 1.0f/(1.0f+expf(-x)); }

// ---------------- init: copy input -> H,C ; init links/logits ----------------
__global__ void k_init(const float* __restrict__ in, const int* __restrict__ len,
                       float* __restrict__ H, float* __restrict__ Cc,
                       float* __restrict__ LG, int* __restrict__ NXT,
                       int* __restrict__ PRV, int4* __restrict__ ROWS)
{
    int bs = blockIdx.x;            // b*48+s
    int b  = bs / NSLOT, s = bs % NSLOT;
    int t  = threadIdx.x;           // 256 threads, 1 float4 each
    const float4* inrow = (const float4*)(in + (size_t)bs*2*HID);
    float4 v = inrow[t];
    if (t < 128) ((float4*)(H  + (size_t)bs*HID))[t]       = v;
    else         ((float4*)(Cc + (size_t)bs*HID))[t - 128] = v;
    if (t == 0) {
        int lb = len[b];
        NXT[bs] = (s+1 < lb) ? s+1 : -1;
        PRV[bs] = (s > 0 && s < lb) ? s-1 : -1;
        LG[bs]  = -FLT_MAX;
        if (s == 0) {
            ROWS[b*2+0] = make_int4(0,0,0,-1);
            ROWS[b*2+1] = make_int4(0,0,0,-1);
        }
    }
}

// ---------------- descriptors + compaction-state zeroing ----------------
__global__ void k_descA(const int* __restrict__ len, int4* __restrict__ ROWSA,
                        int* __restrict__ ROWSN, int* __restrict__ NLIVE,
                        int* __restrict__ NACT, int* __restrict__ PROWC)
{
    __shared__ int off[NB+1];
    int t = threadIdx.x;            // single block, 256 threads
    if (t == 0){
        int acc = 0;
        for (int b=0;b<NB;++b){ off[b]=acc; acc += len[b]; }
        off[NB] = acc;
        NLIVE[0] = (acc + 127) & ~127;
    }
    __syncthreads();
    int nlive = off[NB];
    int npad  = (nlive + 127) & ~127;
    for (int r = t; r < AROWS; r += 256){
        int b = r/(NL-1), s = r%(NL-1);
        int lb = len[b];
        ROWSA[r] = make_int4(b, s, s+1, (s <= lb-2) ? s : -1);
    }
    for (int x = t; x < NNODE; x += 256){
        int b = x / NSLOT, s = x % NSLOT;
        if (s < len[b]) ROWSN[off[b] + s] = x;
    }
    for (int x = nlive + t; x < npad; x += 256) ROWSN[x] = 0;
    for (int x = t; x < 64;   x += 256) NACT[x] = 0;
    for (int x = t; x < 6016; x += 256) PROWC[x] = 0;
}

// ================= phase-A split-W product GEMM (8x4 micro) =================
// PL[node][n] = sum_k H[node][k]*W[n][k],  PR[node][n] = sum_k H[node][k]*W[n][512+k]
template<int MI, int KT>
__global__ __launch_bounds__(256, 6)
void k_gemmP(const int* __restrict__ rows, const int* __restrict__ NLIVE,
             const float* __restrict__ H, const float* __restrict__ W,
             float* __restrict__ PL, float* __restrict__ PR)
{
    constexpr int BM  = 16*MI;
    constexpr int AF4 = BM/64;
    constexpr int LDA = BM + 4;
    constexpr int LDB = 68;

    const int m0  = blockIdx.x*BM;
    if (m0 >= NLIVE[0]) return;     // compacted: skip dead tiles

    __shared__ float As[2][16*LDA];
    __shared__ float Bs[2][16*LDB];

    const int t   = threadIdx.x;
    const int vn0 = blockIdx.y*64;
    const int side = (vn0 >= NN);
    const int n0  = side ? vn0 - NN : vn0;
    float* OUT = side ? PR : PL;

    int aoff[AF4], arow[AF4], aseg[AF4];
    #pragma unroll
    for (int j=0;j<AF4;++j){
        int f = t*AF4 + j;
        arow[j] = f >> 2; aseg[j] = f & 3;
        aoff[j] = rows[m0 + arow[j]]*HID + aseg[j]*4;
    }
    const int brow = t >> 2, bseg = t & 3;
    const float* wptr = W + (size_t)(n0 + brow)*1024 + side*HID + bseg*4;

    const int tm = t >> 4, tn = t & 15;

    float acc[MI][4];
    #pragma unroll
    for (int mi=0;mi<MI;++mi)
        #pragma unroll
        for (int j=0;j<4;++j) acc[mi][j]=0.f;

    float4 av[AF4], bv;
    auto gload = [&](int kt){
        int kg = kt*16;
        #pragma unroll
        for (int j=0;j<AF4;++j) av[j] = *(const float4*)(H + aoff[j] + kg);
        bv = *(const float4*)(wptr + kg);
    };
    auto swrite = [&](int buf){
        #pragma unroll
        for (int j=0;j<AF4;++j){
            As[buf][(aseg[j]*4+0)*LDA + arow[j]] = av[j].x;
            As[buf][(aseg[j]*4+1)*LDA + arow[j]] = av[j].y;
            As[buf][(aseg[j]*4+2)*LDA + arow[j]] = av[j].z;
            As[buf][(aseg[j]*4+3)*LDA + arow[j]] = av[j].w;
        }
        Bs[buf][(bseg*4+0)*LDB + brow] = bv.x;
        Bs[buf][(bseg*4+1)*LDB + brow] = bv.y;
        Bs[buf][(bseg*4+2)*LDB + brow] = bv.z;
        Bs[buf][(bseg*4+3)*LDB + brow] = bv.w;
    };

    gload(0); swrite(0); __syncthreads();

    for (int kt=0; kt<KT; ++kt){
        int buf = kt & 1;
        if (kt+1 < KT) gload(kt+1);
        #pragma unroll
        for (int k=0;k<16;++k){
            float a[MI];
            #pragma unroll
            for (int mi=0;mi<MI;mi+=4){
                float4 a4 = *(const float4*)&As[buf][k*LDA + tm*MI + mi];
                a[mi]=a4.x; a[mi+1]=a4.y; a[mi+2]=a4.z; a[mi+3]=a4.w;
            }
            float4 b4 = *(const float4*)&Bs[buf][k*LDB + tn*4];
            #pragma unroll
            for (int mi=0;mi<MI;++mi){
                acc[mi][0] = fmaf(a[mi], b4.x, acc[mi][0]);
                acc[mi][1] = fmaf(a[mi], b4.y, acc[mi][1]);
                acc[mi][2] = fmaf(a[mi], b4.z, acc[mi][2]);
                acc[mi][3] = fmaf(a[mi], b4.w, acc[mi][3]);
            }
        }
        if (kt+1 < KT) swrite(buf^1);
        __syncthreads();
    }

    #pragma unroll
    for (int mi=0;mi<MI;++mi){
        int row = m0 + tm*MI + mi;
        float4 o; o.x=acc[mi][0]; o.y=acc[mi][1]; o.z=acc[mi][2]; o.w=acc[mi][3];
        *(float4*)(OUT + (size_t)rows[row]*NN + n0 + tn*4) = o;
    }
}

// ================= step GEMM: K-split -> V partials (compacted active rows) =================
// grid (2, 80, KS): BM=64, BN=64, 4x4 micro, K=512/KS per kz.
// row r computes node PROWC[iter*128+r]; V[((kz*2+side)*NB + r)*NN + n] = partial.
template<int KS>
__global__ __launch_bounds__(256, 4)
void k_gemmV(int iter, const int* __restrict__ PROWC, const int* __restrict__ NACT,
             const float* __restrict__ H, const float* __restrict__ W,
             float* __restrict__ V)
{
    constexpr int MI = 4, KT = 32/KS;
    constexpr int LDA = 68;
    constexpr int LDB = 68;

    const int m0  = blockIdx.x*64;
    const int nact = NACT[iter];
    if (m0 >= ((nact + 63) & ~63)) return;   // skip finished-batch tiles

    __shared__ float As[2][16*LDA];
    __shared__ float Bs[2][16*LDB];

    const int t   = threadIdx.x;
    const int vn0 = blockIdx.y*64;
    const int side = (vn0 >= NN);
    const int n0  = side ? vn0 - NN : vn0;
    const int kz  = blockIdx.z;
    const int kg0 = kz*KT*16;

    const int arow = t >> 2, aseg = t & 3;
    const float* aptr = H + (size_t)PROWC[iter*128 + m0 + arow]*HID + aseg*4 + kg0;
    const float* bptr = W + (size_t)(n0 + arow)*1024 + side*HID + aseg*4 + kg0;

    const int tm = t >> 4, tn = t & 15;

    float acc[MI][4];
    #pragma unroll
    for (int mi=0;mi<MI;++mi)
        #pragma unroll
        for (int j=0;j<4;++j) acc[mi][j]=0.f;

    float4 av, bv;
    auto gload = [&](int kt){
        av = *(const float4*)(aptr + kt*16);
        bv = *(const float4*)(bptr + kt*16);
    };
    auto swrite = [&](int buf){
        As[buf][(aseg*4+0)*LDA + arow] = av.x;
        As[buf][(aseg*4+1)*LDA + arow] = av.y;
        As[buf][(aseg*4+2)*LDA + arow] = av.z;
        As[buf][(aseg*4+3)*LDA + arow] = av.w;
        Bs[buf][(aseg*4+0)*LDB + arow] = bv.x;
        Bs[buf][(aseg*4+1)*LDB + arow] = bv.y;
        Bs[buf][(aseg*4+2)*LDB + arow] = bv.z;
        Bs[buf][(aseg*4+3)*LDB + arow] = bv.w;
    };

    gload(0); swrite(0); __syncthreads();

    for (int kt=0; kt<KT; ++kt){
        int buf = kt & 1;
        if (kt+1 < KT) gload(kt+1);
        #pragma unroll
        for (int k=0;k<16;++k){
            float4 a4 = *(const float4*)&As[buf][k*LDA + tm*MI];
            float4 b4 = *(const float4*)&Bs[buf][k*LDB + tn*4];
            float a[4] = {a4.x,a4.y,a4.z,a4.w};
            #pragma unroll
            for (int mi=0;mi<MI;++mi){
                acc[mi][0] = fmaf(a[mi], b4.x, acc[mi][0]);
                acc[mi][1] = fmaf(a[mi], b4.y, acc[mi][1]);
                acc[mi][2] = fmaf(a[mi], b4.z, acc[mi][2]);
                acc[mi][3] = fmaf(a[mi], b4.w, acc[mi][3]);
            }
        }
        if (kt+1 < KT) swrite(buf^1);
        __syncthreads();
    }

    #pragma unroll
    for (int mi=0;mi<MI;++mi){
        int row = m0 + tm*MI + mi;      // compacted row index
        float4 o; o.x=acc[mi][0]; o.y=acc[mi][1]; o.z=acc[mi][2]; o.w=acc[mi][3];
        *(float4*)(V + ((size_t)(kz*2+side)*NB + row)*NN + n0 + tn*4) = o;
    }
}

// ---------------- phase-A combine: v = PL[l]+PR[r]+bias -> gates -> CH/CC + logit ----------------
__global__ void k_combineP(const int4* __restrict__ rows,
                           const float* __restrict__ PL, const float* __restrict__ PR,
                           const float* __restrict__ Cc, const float* __restrict__ bias,
                           const float* __restrict__ q,
                           float* __restrict__ CH, float* __restrict__ CC,
                           float* __restrict__ LG)
{
    int4 rd = rows[blockIdx.x];
    if (rd.w < 0) return;
    int t = threadIdx.x;
    int b = rd.x, sl = rd.y, sr = rd.z, dst = rd.w;
    const float* pl = PL + (size_t)(b*NSLOT+sl)*NN;
    const float* pr = PR + (size_t)(b*NSLOT+sr)*NN;
    const float* cl = Cc + (size_t)(b*NSLOT+sl)*HID;
    const float* cr = Cc + (size_t)(b*NSLOT+sr)*HID;
    int c = t*2;                       // float2 per thread, covers 0..511
    float2 v[5];
    #pragma unroll
    for (int g=0; g<5; ++g){
        float2 a  = *(const float2*)&pl[g*HID + c];
        float2 bb = *(const float2*)&pr[g*HID + c];
        float2 bs = *(const float2*)&bias[g*HID + c];
        v[g].x = a.x + bb.x + bs.x;
        v[g].y = a.y + bb.y + bs.y;
    }
    float2 cl2 = *(const float2*)&cl[c];
    float2 cr2 = *(const float2*)&cr[c];
    float2 q2  = *(const float2*)&q[c];
    float2 cn, hn;
    cn.x = cl2.x*sigf(v[1].x+1.f) + cr2.x*sigf(v[2].x+1.f) + tanhf(v[3].x)*sigf(v[0].x);
    cn.y = cl2.y*sigf(v[1].y+1.f) + cr2.y*sigf(v[2].y+1.f) + tanhf(v[3].y)*sigf(v[0].y);
    hn.x = sigf(v[4].x)*tanhf(cn.x);
    hn.y = sigf(v[4].y)*tanhf(cn.y);
    *(float2*)&CH[(size_t)(b*NSLOT+dst)*HID + c] = hn;
    *(float2*)&CC[(size_t)(b*NSLOT+dst)*HID + c] = cn;
    float part = q2.x*hn.x + q2.y*hn.y;

    __shared__ float red[4];
    #pragma unroll
    for (int off=32; off; off>>=1) part += __shfl_xor(part, off);
    if ((t & 63) == 0) red[t>>6] = part;
    __syncthreads();
    if (t == 0) LG[b*NSLOT + dst] = red[0]+red[1]+red[2]+red[3];
}

// ---------------- step 0: argmax, commit, relink + compaction for iter 1 ----------------
__global__ void k_step0(const int* __restrict__ len,
                        float* __restrict__ H, float* __restrict__ Cc,
                        const float* __restrict__ CH, const float* __restrict__ CC,
                        float* __restrict__ LG, int* __restrict__ NXT,
                        int* __restrict__ PRV, int4* __restrict__ ROWS,
                        int* __restrict__ PROW, int* __restrict__ POSB,
                        int* __restrict__ NACT, int* __restrict__ PROWC)
{
    int b = blockIdx.x, lane = threadIdx.x;   // block = 64 = 1 wave
    int base = b*NSLOT;

    float val = (lane < NSLOT) ? LG[base+lane] : -FLT_MAX;
    int idx = lane;
    for (int off=1; off<64; off<<=1){
        float oval = __shfl_xor(val, off);
        int   oidx = __shfl_xor(idx, off);
        if (oval > val || (oval == val && oidx < idx)){ val = oval; idx = oidx; }
    }
    int sstar = idx;
    int r  = NXT[base+sstar];
    int qn = NXT[base+r];
    int p  = PRV[base+sstar];

    const float4* sh = (const float4*)(CH + (size_t)(base+sstar)*HID);
    const float4* sc = (const float4*)(CC + (size_t)(base+sstar)*HID);
    float4* dh = (float4*)(H  + (size_t)(base+sstar)*HID);
    float4* dc = (float4*)(Cc + (size_t)(base+sstar)*HID);
    dh[lane] = sh[lane]; dh[lane+64] = sh[lane+64];
    dc[lane] = sc[lane]; dc[lane+64] = sc[lane+64];

    if (lane==0){
        NXT[base+sstar] = qn;
        if (qn >= 0) PRV[base+qn] = sstar;
        LG[base+r] = -FLT_MAX;
        if (qn < 0) LG[base+sstar] = -FLT_MAX;
        ROWS[b*2+0] = (p  >= 0) ? make_int4(b, p, sstar, p)      : make_int4(0,0,0,-1);
        ROWS[b*2+1] = (qn >= 0) ? make_int4(b, sstar, qn, sstar) : make_int4(0,0,0,-1);
        PROW[b] = base + sstar;
        // every batch is active at iter 1 (len >= 24)
        int pos = atomicAdd(&NACT[1], 1);
        PROWC[128 + pos] = base + sstar;
        POSB[b] = pos;
    }
}

// ---------------- fused combine+step: 512 threads, pairs in parallel ----------------
// threads 0-255: pair 0 (p,new) needs PRnew (side 1); 256-511: pair 1 (new,qn) needs PLnew (side 0).
template<int KS>
__global__ __launch_bounds__(512, 2)
void k_combineStep(int i, const int* __restrict__ len,
                   const float* __restrict__ V,
                   float* __restrict__ PL, float* __restrict__ PR,
                   int4* __restrict__ ROWS, int* __restrict__ PROW,
                   float* __restrict__ H, float* __restrict__ Cc,
                   float* __restrict__ CH, float* __restrict__ CC,
                   float* __restrict__ LG, int* __restrict__ NXT,
                   int* __restrict__ PRV,
                   const float* __restrict__ bias, const float* __restrict__ q,
                   int* __restrict__ POSB, int* __restrict__ NACT,
                   int* __restrict__ PROWC)
{
    int b = blockIdx.x, t = threadIdx.x;
    int base = b*NSLOT;
    int e = t >> 8, u = t & 255;
    int4 rd = ROWS[b*2+e];
    bool valid = (rd.w >= 0);
    int node = PROW[b];
    __shared__ float slg[NSLOT];
    __shared__ float red[8];
    __shared__ int ss[1];

    // sum V partials for my side; write-through to cache. Only if this pair is live:
    // e=0 invalid <=> node is leftmost <=> PR[node] never needed (sym. for e=1/PL).
    int side = (e == 0) ? 1 : 0;
    float* CACHE = (e == 0) ? PR : PL;
    float vnew[10];
    float part = 0.f;
    if (valid){
        int vrow = POSB[b];
        #pragma unroll
        for (int jj=0;jj<10;++jj){
            int c = jj*256 + u;
            float s = 0.f;
            #pragma unroll
            for (int kz=0; kz<KS; ++kz)
                s += V[((size_t)(kz*2+side)*NB + vrow)*NN + c];
            vnew[jj] = s;
            CACHE[(size_t)node*NN + c] = s;
        }
        const float* OTH = e ? (PR + (size_t)(base+rd.z)*NN)
                             : (PL + (size_t)(base+rd.y)*NN);
        const float* cl = Cc + (size_t)(base+rd.y)*HID;
        const float* cr = Cc + (size_t)(base+rd.z)*HID;
        int dst = rd.w;
        #pragma unroll
        for (int h2=0; h2<2; ++h2){
            int c = u + h2*256;
            float v[5];
            #pragma unroll
            for (int g=0; g<5; ++g)
                v[g] = OTH[g*HID + c] + vnew[g*2+h2] + bias[g*HID + c];
            float cn = cl[c]*sigf(v[1]+1.f) + cr[c]*sigf(v[2]+1.f) + tanhf(v[3])*sigf(v[0]);
            float hn = sigf(v[4])*tanhf(cn);
            CH[(size_t)(base+dst)*HID + c] = hn;
            CC[(size_t)(base+dst)*HID + c] = cn;
            part += q[c]*hn;
        }
    }
    #pragma unroll
    for (int off=32; off; off>>=1) part += __shfl_xor(part, off);
    if ((t & 63) == 0) red[t>>6] = part;
    if (t < NSLOT) slg[t] = LG[base+t];
    __syncthreads();

    if (t == 0){
        int4 r1 = ROWS[b*2+1];
        float s0 = red[0]+red[1]+red[2]+red[3];
        float s1 = red[4]+red[5]+red[6]+red[7];
        if (rd.w >= 0){ LG[base+rd.w]=s0; slg[rd.w]=s0; }      // pair 0 (t==0 has e=0)
        if (r1.w >= 0){ LG[base+r1.w]=s1; slg[r1.w]=s1; }
    }
    __syncthreads();

    int lb = len[b];
    if (i > lb-2){
        if (t==0){
            ROWS[b*2+0]=make_int4(0,0,0,-1);
            ROWS[b*2+1]=make_int4(0,0,0,-1);
            PROW[b]=base;
        }
        return;
    }

    if (t < 64){
        float val = (t < NSLOT)? slg[t] : -FLT_MAX;
        int idx = t;
        for (int off=1; off<64; off<<=1){
            float ov=__shfl_xor(val,off); int oi=__shfl_xor(idx,off);
            if (ov>val || (ov==val && oi<idx)){ val=ov; idx=oi; }
        }
        if (t==0) ss[0]=idx;
    }
    __syncthreads();
    int sstar = ss[0];
    {
        const float4* sh = (const float4*)(CH + (size_t)(base+sstar)*HID);
        const float4* sc = (const float4*)(CC + (size_t)(base+sstar)*HID);
        float4* dh = (float4*)(H  + (size_t)(base+sstar)*HID);
        float4* dc = (float4*)(Cc + (size_t)(base+sstar)*HID);
        if (t < 128)      dh[t] = sh[t];
        else if (t < 256) dc[t-128] = sc[t-128];
    }
    if (t == 0){
        int r  = NXT[base+sstar];
        int qn = NXT[base+r];
        int p  = PRV[base+sstar];
        NXT[base+sstar] = qn;
        if (qn >= 0) PRV[base+qn] = sstar;
        LG[base+r] = -FLT_MAX;
        if (qn < 0) LG[base+sstar] = -FLT_MAX;
        ROWS[b*2+0] = (p  >= 0) ? make_int4(b, p, sstar, p)      : make_int4(0,0,0,-1);
        ROWS[b*2+1] = (qn >= 0) ? make_int4(b, sstar, qn, sstar) : make_int4(0,0,0,-1);
        PROW[b] = base + sstar;
        if (i <= lb-3){                      // active at iter i+1
            int pos = atomicAdd(&NACT[i+1], 1);
            PROWC[(i+1)*128 + pos] = base + sstar;
            POSB[b] = pos;
        }
    }
}

// ---------------- output: root = slot 0 ----------------
__global__ void k_out(const float* __restrict__ H, float* __restrict__ out)
{
    int b = blockIdx.x, t = threadIdx.x;       // 128 threads x float4
    ((float4*)out)[b*128 + t] = ((const float4*)(H + (size_t)b*NSLOT*HID))[t];
}

extern "C" void kernel_launch(void* const* d_in, const int* in_sizes, int n_in,
                              void* d_out, int out_size, void* d_ws, size_t ws_size,
                              hipStream_t stream)
{
    const float* in   = (const float*)d_in[0];
    const float* W    = (const float*)d_in[1];
    const float* bias = (const float*)d_in[2];
    const float* q    = (const float*)d_in[3];
    const int*   len  = (const int*)d_in[4];

    float* ws = (float*)d_ws;
    float* H  = ws + offH;
    float* Cc = ws + offC;
    float* CH = ws + offCH;
    float* CC = ws + offCC;
    float* LG = ws + offLG;
    int* NXT  = (int*)(ws + offNXT);
    int* PRV  = (int*)(ws + offPRV);
    int4* ROWS  = (int4*)(ws + offROWS);
    int4* ROWSA = (int4*)(ws + offROWSA);
    int*  ROWSN = (int*)(ws + offROWSN);
    int*  PROW  = (int*)(ws + offPROW);
    int*  NLIVE = (int*)(ws + offNLIV);
    int*  POSB  = (int*)(ws + offPOSB);
    int*  NACT  = (int*)(ws + offNACT);
    int*  PROWC = (int*)(ws + offPRWC);
    float* V  = ws + offV;
    float* out = (float*)d_out;

    // choose K-split by available workspace
    const size_t vsz2 = (size_t)4*NB*NN;
    const size_t vsz4 = (size_t)8*NB*NN;
    const size_t plprsz = (size_t)2*NNODE*NN;
    const bool ks4 = (ws_size >= (offV + vsz4 + plprsz)*sizeof(float));
    float* PL = ws + offV + (ks4 ? vsz4 : vsz2);
    float* PR = PL + (size_t)NNODE*NN;

    k_init <<<dim3(NNODE), dim3(256), 0, stream>>>(in, len, H, Cc, LG, NXT, PRV, ROWS);
    k_descA<<<dim3(1), dim3(256), 0, stream>>>(len, ROWSA, ROWSN, NLIVE, NACT, PROWC);

    // phase A: per-node products (compacted rows) + pair combine + first merge
    k_gemmP<8,32><<<dim3(NNODE/128, 2*NN/64), dim3(256), 0, stream>>>(ROWSN, NLIVE, H, W, PL, PR);
    k_combineP<<<dim3(AROWS), dim3(256), 0, stream>>>(ROWSA, PL, PR, Cc, bias, q, CH, CC, LG);
    k_step0<<<dim3(NB), dim3(64), 0, stream>>>(len, H, Cc, CH, CC, LG, NXT, PRV, ROWS, PROW,
                                               POSB, NACT, PROWC);

    // step loop: 2 kernels per iteration
    if (ks4){
        for (int i = 1; i < NL-1; ++i){
            k_gemmV<4><<<dim3(2, 2*NN/64, 4), dim3(256), 0, stream>>>(i, PROWC, NACT, H, W, V);
            k_combineStep<4><<<dim3(NB), dim3(512), 0, stream>>>(
                i, len, V, PL, PR, ROWS, PROW, H, Cc, CH, CC, LG, NXT, PRV, bias, q,
                POSB, NACT, PROWC);
        }
    } else {
        for (int i = 1; i < NL-1; ++i){
            k_gemmV<2><<<dim3(2, 2*NN/64, 2), dim3(256), 0, stream>>>(i, PROWC, NACT, H, W, V);
            k_combineStep<2><<<dim3(NB), dim3(512), 0, stream>>>(
                i, len, V, PL, PR, ROWS, PROW, H, Cc, CH, CC, LG, NXT, PRV, bias, q,
                POSB, NACT, PROWC);
        }
    }
    k_out<<<dim3(NB), dim3(128), 0, stream>>>(H, out);
}